// Round 7
// baseline (153.405 us; speedup 1.0000x reference)
//
#include <hip/hip_runtime.h>
#include <math.h>

// DynamicAttention1 — round 18b: RESUBMIT of R18 (acquisition timeout, no data).
// 3-stage pipeline, prep eliminated:
//   - R17 proved in-loop fp32->bf16 cvt is latency-hidden (free) -> consume
//     query/src/trg RAW with cvt8 in the staging loaders.
//   - keys/qh GEMMs take B from RAW Ws/Wq via transpose-on-LDS-write:
//     thread loads 16 k-contiguous fp32 of one B-column (strided dwords,
//     4x64B segments per wave per load), cvt, writes 2x ds_write_b128 into
//     the Bs[n][k] layout the MFMA fragment reads already use.
//   - WoT transpose (needed by Pgemm/out_left in S2) rides inside S1.
//   S1: keys (200 blk x 32it) + qh (256 blk x 8it) + WoT transpose (512 blk)
//   S2: scgemm (128) + Pgemm (200) + out_left (256)   [all 8-iter]
//   S3: softmax + wP -> atomic out (512 blk)
// keys UNBIASED everywhere (bs cancels in score diff and in ctx); bq/bo kept.
// Numerically identical to R17 (same RNE roundings) -> absmax ~0.0156.
// Prediction: 133.4 -> ~112-120us (one boundary + prep kernel removed).

typedef __attribute__((ext_vector_type(8))) short s16x8;
typedef __attribute__((ext_vector_type(4))) float f32x4;

__device__ __forceinline__ unsigned short f2bf(float f) {
    unsigned int u = __float_as_uint(f);
    return (unsigned short)((u + 0x7fffu + ((u >> 16) & 1u)) >> 16);  // RNE
}

__device__ __forceinline__ s16x8 cvt8(const float* p) {
    float4 u = *(const float4*)p, w = *(const float4*)(p + 4);
    s16x8 o;
    o[0] = (short)f2bf(u.x); o[1] = (short)f2bf(u.y);
    o[2] = (short)f2bf(u.z); o[3] = (short)f2bf(u.w);
    o[4] = (short)f2bf(w.x); o[5] = (short)f2bf(w.y);
    o[6] = (short)f2bf(w.z); o[7] = (short)f2bf(w.w);
    return o;
}

// ---------------- keys GEMM: A=[src;trg] raw fp32, B=raw Ws (write-transp) --
// 64x64 tile, 4 waves 2x2; K=2048 (32 iters), bf16 epilogue.
__device__ __forceinline__ void gemm64_keys(
    const float* __restrict__ src, const float* __restrict__ trg,
    const float* __restrict__ Ws, unsigned short* __restrict__ Kb,
    int m0, int n0, unsigned short* As, unsigned short* Bs) {
    const int t = threadIdx.x;
    const int lane = t & 63, wid = t >> 6;
    const int wm = (wid & 1) * 32, wn = (wid >> 1) * 32;
    const int lr = lane & 15, lq = lane >> 4;
    const int r = t >> 3, c8 = (t & 7) * 8;      // A staging coords
    const int nrow = t >> 2, kc16 = (t & 3) * 16;  // B staging coords

    const int ra_row = m0 + r, rb_row = m0 + r + 32;
    const float* arp = (ra_row < 800) ? (src + (size_t)ra_row * 2048)
                                      : (trg + (size_t)(ra_row - 800) * 2048);
    const float* brp = (rb_row < 800) ? (src + (size_t)rb_row * 2048)
                                      : (trg + (size_t)(rb_row - 800) * 2048);

    s16x8 ra0, ra1;
    float bw[16];
#define LDK(kt)                                                              \
    ra0 = cvt8(arp + (kt) + c8);                                             \
    ra1 = cvt8(brp + (kt) + c8);                                             \
    _Pragma("unroll")                                                        \
    for (int j = 0; j < 16; j++)                                             \
        bw[j] = Ws[(size_t)((kt) + kc16 + j) * 512 + n0 + nrow];

    f32x4 acc[2][2] = {};
    LDK(0);
    for (int it = 0; it < 32; it++) {
        __syncthreads();
        *(s16x8*)&As[r * 72 + c8]        = ra0;
        *(s16x8*)&As[(r + 32) * 72 + c8] = ra1;
        {   // B: cvt 16 fp32 -> 2 x b128 transposed writes (Bs[n][k])
            s16x8 bb0, bb1;
#pragma unroll
            for (int j = 0; j < 8; j++) {
                bb0[j] = (short)f2bf(bw[j]);
                bb1[j] = (short)f2bf(bw[8 + j]);
            }
            *(s16x8*)&Bs[nrow * 72 + kc16]     = bb0;
            *(s16x8*)&Bs[nrow * 72 + kc16 + 8] = bb1;
        }
        __syncthreads();
        if (it < 31) { LDK((it + 1) * 64); }  // prefetch
#pragma unroll
        for (int s = 0; s < 2; s++) {
            s16x8 a0 = *(const s16x8*)&As[(wm + lr) * 72      + s * 32 + lq * 8];
            s16x8 a1 = *(const s16x8*)&As[(wm + 16 + lr) * 72 + s * 32 + lq * 8];
            s16x8 b0 = *(const s16x8*)&Bs[(wn + lr) * 72      + s * 32 + lq * 8];
            s16x8 b1 = *(const s16x8*)&Bs[(wn + 16 + lr) * 72 + s * 32 + lq * 8];
            acc[0][0] = __builtin_amdgcn_mfma_f32_16x16x32_bf16(a0, b0, acc[0][0], 0, 0, 0);
            acc[0][1] = __builtin_amdgcn_mfma_f32_16x16x32_bf16(a0, b1, acc[0][1], 0, 0, 0);
            acc[1][0] = __builtin_amdgcn_mfma_f32_16x16x32_bf16(a1, b0, acc[1][0], 0, 0, 0);
            acc[1][1] = __builtin_amdgcn_mfma_f32_16x16x32_bf16(a1, b1, acc[1][1], 0, 0, 0);
        }
    }
#undef LDK
#pragma unroll
    for (int i = 0; i < 2; i++)
#pragma unroll
        for (int j = 0; j < 2; j++) {
            const int col = n0 + wn + j * 16 + lr;      // C/D: col=lane&15
            const int row = m0 + wm + i * 16 + lq * 4;  //      row=quad*4+reg
#pragma unroll
            for (int rr = 0; rr < 4; rr++)
                Kb[(size_t)(row + rr) * 512 + col] = f2bf(acc[i][j][rr]);
        }
}

// ---------------- qh GEMM: A=raw query, B=raw Wq (write-transpose) ----------
// 32x64 tile, 4 waves, K=512 (8 iters), bf16+bias epilogue.
__device__ __forceinline__ void gemm32_rawB(
    const float* __restrict__ A, const float* __restrict__ W,
    const float* __restrict__ bias, unsigned short* __restrict__ C,
    int m0, int n0, unsigned short* As, unsigned short* Bs) {
    const int t = threadIdx.x;
    const int lane = t & 63, wid = t >> 6;
    const int wm = (wid & 1) * 16, wn = (wid >> 1) * 32;
    const int lr = lane & 15, lq = lane >> 4;
    const int r = t >> 3, c8 = (t & 7) * 8;
    const int nrow = t >> 2, kc16 = (t & 3) * 16;

    s16x8 ra;
    float bw[16];
#define LDQ(kt)                                                              \
    ra = cvt8(A + (size_t)(m0 + r) * 512 + (kt) + c8);                       \
    _Pragma("unroll")                                                        \
    for (int j = 0; j < 16; j++)                                             \
        bw[j] = W[(size_t)((kt) + kc16 + j) * 512 + n0 + nrow];

    f32x4 acc[2] = {};
    LDQ(0);
    for (int it = 0; it < 8; it++) {
        __syncthreads();
        *(s16x8*)&As[r * 72 + c8] = ra;
        {
            s16x8 bb0, bb1;
#pragma unroll
            for (int j = 0; j < 8; j++) {
                bb0[j] = (short)f2bf(bw[j]);
                bb1[j] = (short)f2bf(bw[8 + j]);
            }
            *(s16x8*)&Bs[nrow * 72 + kc16]     = bb0;
            *(s16x8*)&Bs[nrow * 72 + kc16 + 8] = bb1;
        }
        __syncthreads();
        if (it < 7) { LDQ((it + 1) * 64); }  // prefetch
#pragma unroll
        for (int s = 0; s < 2; s++) {
            s16x8 a0 = *(const s16x8*)&As[(wm + lr) * 72      + s * 32 + lq * 8];
            s16x8 b0 = *(const s16x8*)&Bs[(wn + lr) * 72      + s * 32 + lq * 8];
            s16x8 b1 = *(const s16x8*)&Bs[(wn + 16 + lr) * 72 + s * 32 + lq * 8];
            acc[0] = __builtin_amdgcn_mfma_f32_16x16x32_bf16(a0, b0, acc[0], 0, 0, 0);
            acc[1] = __builtin_amdgcn_mfma_f32_16x16x32_bf16(a0, b1, acc[1], 0, 0, 0);
        }
    }
#undef LDQ
#pragma unroll
    for (int j = 0; j < 2; j++) {
        const int col = n0 + wn + j * 16 + lr;
        const int row = m0 + wm + lq * 4;
        const float bv = bias[col];
#pragma unroll
        for (int rr = 0; rr < 4; rr++)
            C[(size_t)(row + rr) * 512 + col] = f2bf(acc[j][rr] + bv);
    }
}

// ---------------- out_left GEMM: A=raw query, BT=wot bf16, fp32+bias --------
__device__ __forceinline__ void gemm32_cvtA(
    const float* __restrict__ A, const unsigned short* __restrict__ BT,
    const float* __restrict__ bias, float* __restrict__ C,
    int m0, int n0, int KB, unsigned short* As, unsigned short* Bs) {
    const int t = threadIdx.x;
    const int lane = t & 63, wid = t >> 6;
    const int wm = (wid & 1) * 16, wn = (wid >> 1) * 32;
    const int lr = lane & 15, lq = lane >> 4;
    const int r = t >> 3, c8 = (t & 7) * 8;

    s16x8 ra, rb0, rb1;
#define LD32(kt)                                                            \
    ra  = cvt8(A + (size_t)(m0 + r) * 512 + (kt) + c8);                     \
    rb0 = *(const s16x8*)(BT + (size_t)(n0 + r)      * KB + (kt) + c8);     \
    rb1 = *(const s16x8*)(BT + (size_t)(n0 + r + 32) * KB + (kt) + c8);

    f32x4 acc[2] = {};
    LD32(0);
    for (int it = 0; it < 8; it++) {
        __syncthreads();
        *(s16x8*)&As[r * 72 + c8]        = ra;
        *(s16x8*)&Bs[r * 72 + c8]        = rb0;
        *(s16x8*)&Bs[(r + 32) * 72 + c8] = rb1;
        __syncthreads();
        if (it < 7) { LD32((it + 1) * 64); }  // prefetch
#pragma unroll
        for (int s = 0; s < 2; s++) {
            s16x8 a0 = *(const s16x8*)&As[(wm + lr) * 72      + s * 32 + lq * 8];
            s16x8 b0 = *(const s16x8*)&Bs[(wn + lr) * 72      + s * 32 + lq * 8];
            s16x8 b1 = *(const s16x8*)&Bs[(wn + 16 + lr) * 72 + s * 32 + lq * 8];
            acc[0] = __builtin_amdgcn_mfma_f32_16x16x32_bf16(a0, b0, acc[0], 0, 0, 0);
            acc[1] = __builtin_amdgcn_mfma_f32_16x16x32_bf16(a0, b1, acc[1], 0, 0, 0);
        }
    }
#undef LD32
#pragma unroll
    for (int j = 0; j < 2; j++) {
        const int col = n0 + wn + j * 16 + lr;
        const int row = m0 + wm + lq * 4;
        const float bv = bias[col];
#pragma unroll
        for (int rr = 0; rr < 4; rr++)
            C[(size_t)(row + rr) * 512 + col] = acc[j][rr] + bv;
    }
}

// ---------------- P GEMM: P = keys(bf16) @ WoBot (wot+512), fp32 store ------
__device__ __forceinline__ void gemm64_P(
    const unsigned short* __restrict__ Kb, const unsigned short* __restrict__ wotBot,
    float* __restrict__ P, int m0, int n0, unsigned short* As,
    unsigned short* Bs) {
    const int t = threadIdx.x;
    const int lane = t & 63, wid = t >> 6;
    const int wm = (wid & 1) * 32, wn = (wid >> 1) * 32;
    const int lr = lane & 15, lq = lane >> 4;
    const int r = t >> 3, c8 = (t & 7) * 8;

    s16x8 ra0, ra1, rb0, rb1;
#define LDP(kt)                                                               \
    ra0 = *(const s16x8*)(Kb + (size_t)(m0 + r)      * 512 + (kt) + c8);      \
    ra1 = *(const s16x8*)(Kb + (size_t)(m0 + r + 32) * 512 + (kt) + c8);      \
    rb0 = *(const s16x8*)(wotBot + (size_t)(n0 + r)      * 1024 + (kt) + c8); \
    rb1 = *(const s16x8*)(wotBot + (size_t)(n0 + r + 32) * 1024 + (kt) + c8);

    f32x4 acc[2][2] = {};
    LDP(0);
    for (int it = 0; it < 8; it++) {
        __syncthreads();
        *(s16x8*)&As[r * 72 + c8]        = ra0;
        *(s16x8*)&As[(r + 32) * 72 + c8] = ra1;
        *(s16x8*)&Bs[r * 72 + c8]        = rb0;
        *(s16x8*)&Bs[(r + 32) * 72 + c8] = rb1;
        __syncthreads();
        if (it < 7) { LDP((it + 1) * 64); }  // prefetch
#pragma unroll
        for (int s = 0; s < 2; s++) {
            s16x8 a0 = *(const s16x8*)&As[(wm + lr) * 72      + s * 32 + lq * 8];
            s16x8 a1 = *(const s16x8*)&As[(wm + 16 + lr) * 72 + s * 32 + lq * 8];
            s16x8 b0 = *(const s16x8*)&Bs[(wn + lr) * 72      + s * 32 + lq * 8];
            s16x8 b1 = *(const s16x8*)&Bs[(wn + 16 + lr) * 72 + s * 32 + lq * 8];
            acc[0][0] = __builtin_amdgcn_mfma_f32_16x16x32_bf16(a0, b0, acc[0][0], 0, 0, 0);
            acc[0][1] = __builtin_amdgcn_mfma_f32_16x16x32_bf16(a0, b1, acc[0][1], 0, 0, 0);
            acc[1][0] = __builtin_amdgcn_mfma_f32_16x16x32_bf16(a1, b0, acc[1][0], 0, 0, 0);
            acc[1][1] = __builtin_amdgcn_mfma_f32_16x16x32_bf16(a1, b1, acc[1][1], 0, 0, 0);
        }
    }
#undef LDP
#pragma unroll
    for (int i = 0; i < 2; i++)
#pragma unroll
        for (int j = 0; j < 2; j++) {
            const int col = n0 + wn + j * 16 + lr;
            const int row = m0 + wm + i * 16 + lq * 4;
#pragma unroll
            for (int rr = 0; rr < 4; rr++)
                P[(size_t)(row + rr) * 512 + col] = acc[i][j][rr];
        }
}

// ---------------- S1: keys (200) + qh (256) + WoT transpose (512) -----------
__global__ __launch_bounds__(256) void k_stage1(
    const float* __restrict__ query, const float* __restrict__ src,
    const float* __restrict__ trg, const float* __restrict__ Wq,
    const float* __restrict__ Ws, const float* __restrict__ Wo,
    const float* __restrict__ bq, unsigned short* __restrict__ qh,
    unsigned short* __restrict__ keysbf, unsigned short* __restrict__ wot) {
    __shared__ __align__(16) unsigned short As[64 * 72];
    __shared__ __align__(16) unsigned short Bs[64 * 72];
    const int bid = blockIdx.x, t = threadIdx.x;

    if (bid < 200) {
        gemm64_keys(src, trg, Ws, keysbf, (bid >> 3) * 64, (bid & 7) * 64,
                    As, Bs);
    } else if (bid < 456) {
        const int rr = bid - 200;
        gemm32_rawB(query, Wq, bq, qh, (rr >> 3) * 32, (rr & 7) * 64, As, Bs);
    } else {
        // WoT transpose: Wo[1024][512] -> wot[n=512][k=1024], 32x32 tiles
        float (*tile)[33] = (float(*)[33])As;   // 4.2KB alias over As
        const int id2 = bid - 456;              // 0..511
        const int tk = id2 >> 4, tn = id2 & 15;
        const int row = t >> 3, c4 = (t & 7) * 4;
        float4 v = *(const float4*)(Wo + (size_t)(tk * 32 + row) * 512 + tn * 32 + c4);
        tile[row][c4 + 0] = v.x; tile[row][c4 + 1] = v.y;
        tile[row][c4 + 2] = v.z; tile[row][c4 + 3] = v.w;
        __syncthreads();
        ushort4 o = make_ushort4(f2bf(tile[c4 + 0][row]), f2bf(tile[c4 + 1][row]),
                                 f2bf(tile[c4 + 2][row]), f2bf(tile[c4 + 3][row]));
        *(ushort4*)(wot + (size_t)(tn * 32 + row) * 1024 + tk * 32 + c4) = o;
    }
}

// ---------------- S2: scgemm (128) + Pgemm (200) + out_left (256) -----------
__global__ __launch_bounds__(256) void k_stage2(
    const float* __restrict__ query, const unsigned short* __restrict__ qh,
    const unsigned short* __restrict__ keysbf,
    const unsigned short* __restrict__ wot, const float* __restrict__ bo,
    float* __restrict__ sc, float* __restrict__ P, float* __restrict__ out) {
    __shared__ __align__(16) unsigned short As[64 * 72];
    __shared__ __align__(16) unsigned short Bs[64 * 72];
    const int bid = blockIdx.x;
    const int t = threadIdx.x;

    if (bid >= 328) {                       // ---- out_left ----
        const int rr = bid - 328;
        gemm32_cvtA(query, wot, bo, out, (rr >> 3) * 32, (rr & 7) * 64, 1024,
                    As, Bs);
        return;
    }
    if (bid >= 128) {                       // ---- Pgemm ----
        const int rem = bid - 128;
        gemm64_P(keysbf, wot + 512, P, (rem >> 3) * 64, (rem & 7) * 64, As, Bs);
        return;
    }

    // ---- scgemm: sc cols 0..99 = qs/32, 128..227 = -qt/32 ----
    const int mt = bid >> 2, nt = bid & 3;
    const int m0 = mt * 32, b = mt >> 2, n0 = nt * 64;
    const int lane = t & 63, wid = t >> 6;
    const int wm = (wid & 1) * 16, wn = (wid >> 1) * 32;
    const int lr = lane & 15, lq = lane >> 4;
    const int r = t >> 3, c8 = (t & 7) * 8;

    const int nA = n0 + r, nB = n0 + r + 32;
    int kr0 = (nA < 128) ? (b * 100 + nA) : (800 + b * 100 + (nA - 128));
    int kr1 = (nB < 128) ? (b * 100 + nB) : (800 + b * 100 + (nB - 128));
    kr0 = kr0 > 1599 ? 1599 : kr0;
    kr1 = kr1 > 1599 ? 1599 : kr1;

    s16x8 ra, rb0, rb1;
#define LDSC(kt)                                                        \
    ra  = *(const s16x8*)(qh + (size_t)(m0 + r) * 512 + (kt) + c8);     \
    rb0 = *(const s16x8*)(keysbf + (size_t)kr0 * 512 + (kt) + c8);      \
    rb1 = *(const s16x8*)(keysbf + (size_t)kr1 * 512 + (kt) + c8);

    f32x4 acc[2] = {};
    LDSC(0);
    for (int it = 0; it < 8; it++) {
        __syncthreads();
        *(s16x8*)&As[r * 72 + c8]        = ra;
        *(s16x8*)&Bs[r * 72 + c8]        = rb0;
        *(s16x8*)&Bs[(r + 32) * 72 + c8] = rb1;
        __syncthreads();
        if (it < 7) { LDSC((it + 1) * 64); }
#pragma unroll
        for (int s = 0; s < 2; s++) {
            s16x8 a0 = *(const s16x8*)&As[(wm + lr) * 72      + s * 32 + lq * 8];
            s16x8 b0 = *(const s16x8*)&Bs[(wn + lr) * 72      + s * 32 + lq * 8];
            s16x8 b1 = *(const s16x8*)&Bs[(wn + 16 + lr) * 72 + s * 32 + lq * 8];
            acc[0] = __builtin_amdgcn_mfma_f32_16x16x32_bf16(a0, b0, acc[0], 0, 0, 0);
            acc[1] = __builtin_amdgcn_mfma_f32_16x16x32_bf16(a0, b1, acc[1], 0, 0, 0);
        }
    }
#undef LDSC
#pragma unroll
    for (int j = 0; j < 2; j++) {
        const int col = n0 + wn + j * 16 + lr;
        const int row = m0 + wm + lq * 4;
        const float scale = (col >= 128) ? -(1.0f / 32.0f) : (1.0f / 32.0f);
#pragma unroll
        for (int rr = 0; rr < 4; rr++)
            sc[(size_t)(row + rr) * 256 + col] = acc[j][rr] * scale;
    }
}

// ---------------- S3: softmax + wP GEMM -> atomic into out ------------------
// grid (16 n-tiles, 8 b, 4 l-tiles) = 512 blocks of 32(l) x 32(n), K=200.
__global__ __launch_bounds__(256) void k_stageD(
    const float* __restrict__ sc, const float* __restrict__ P,
    float* __restrict__ out) {
    __shared__ float wbuf[200 * 33];     // [st][l], pad 33
    __shared__ float Bs[40 * 32];        // [k][n]

    const int t = threadIdx.x;
    const int b = blockIdx.y;
    const int n0 = blockIdx.x * 32;
    const int l0 = blockIdx.z * 32;
    const int wave = t >> 6, lane = t & 63;

    // ---- softmax: each wave handles 8 rows; lane covers cols lane*4..+3 ----
    for (int i = 0; i < 8; i++) {
        const int li = wave * 8 + i;                  // 0..31
        const float4 v = *(const float4*)(
            sc + (size_t)(b * 128 + l0 + li) * 256 + lane * 4);
        const float vv[4] = {v.x, v.y, v.z, v.w};
        const int c0 = lane * 4;
        float mS = -1e30f, mT = -1e30f;
#pragma unroll
        for (int j = 0; j < 4; j++) {
            const int col = c0 + j;
            if (col < 100) mS = fmaxf(mS, vv[j]);
            if (col >= 128 && col < 228) mT = fmaxf(mT, vv[j]);
        }
#pragma unroll
        for (int off = 32; off > 0; off >>= 1) {
            mS = fmaxf(mS, __shfl_xor(mS, off));
            mT = fmaxf(mT, __shfl_xor(mT, off));
        }
        float eS[4], eT[4], sS = 0.f, sT = 0.f;
#pragma unroll
        for (int j = 0; j < 4; j++) {
            const int col = c0 + j;
            eS[j] = (col < 100) ? __expf(vv[j] - mS) : 0.f;
            eT[j] = (col >= 128 && col < 228) ? __expf(vv[j] - mT) : 0.f;
            sS += eS[j]; sT += eT[j];
        }
#pragma unroll
        for (int off = 32; off > 0; off >>= 1) {
            sS += __shfl_xor(sS, off);
            sT += __shfl_xor(sT, off);
        }
        const float iS = 1.f / sS, iT = 1.f / sT;
#pragma unroll
        for (int j = 0; j < 4; j++) {
            const int col = c0 + j;
            if (col < 100) wbuf[col * 33 + li] = eS[j] * iS;
            if (col >= 128 && col < 228)
                wbuf[(100 + col - 128) * 33 + li] = eT[j] * iT;
        }
    }
    __syncthreads();

    // ---- GEMM: acc[l][n] += w[st][l] * (+P_s|-P_t)[st][n] ------------------
    const int tx = t & 7, ty = t >> 3;   // tx: n/4, ty: l
    float rB[5];
    auto loadB = [&](int kbase) {
#pragma unroll
        for (int e = 0; e < 5; e++) {
            const int idx = t + e * 256;
            const int k = idx >> 5, j = idx & 31;
            const int kk = kbase + k;
            rB[e] = (kk < 100)
                ?  P[(size_t)(b * 100 + kk) * 512 + n0 + j]
                : -P[(size_t)(800 + b * 100 + (kk - 100)) * 512 + n0 + j];
        }
    };

    float acc[4] = {};
    loadB(0);
    for (int c5 = 0; c5 < 5; c5++) {
        __syncthreads();
#pragma unroll
        for (int e = 0; e < 5; e++) {
            const int idx = t + e * 256;
            Bs[idx] = rB[e];
        }
        __syncthreads();
        if (c5 < 4) loadB((c5 + 1) * 40);          // prefetch next chunk
#pragma unroll 8
        for (int k = 0; k < 40; k++) {
            const float ar = wbuf[(c5 * 40 + k) * 33 + ty];
            float br[4];
            *(float4*)br = *(const float4*)&Bs[k * 32 + tx * 4];
#pragma unroll
            for (int j = 0; j < 4; j++) acc[j] = fmaf(ar, br[j], acc[j]);
        }
    }

    const float s2 = 0.70710678118654752f;  // 1/sqrt(2)
    const int m = b * 128 + l0 + ty;
#pragma unroll
    for (int j = 0; j < 4; j++)
        unsafeAtomicAdd(&out[(size_t)m * 512 + n0 + tx * 4 + j], acc[j] * s2);
}

// ---------------- launch ----------------------------------------------------

extern "C" void kernel_launch(void* const* d_in, const int* in_sizes, int n_in,
                              void* d_out, int out_size, void* d_ws, size_t ws_size,
                              hipStream_t stream) {
    const float* query = (const float*)d_in[0];
    const float* src   = (const float*)d_in[1];
    const float* trg   = (const float*)d_in[2];
    const float* Wq    = (const float*)d_in[3];
    const float* bq    = (const float*)d_in[4];
    const float* Ws    = (const float*)d_in[5];
    const float* Wo    = (const float*)d_in[7];
    const float* bo    = (const float*)d_in[8];
    float* out = (float*)d_out;

    // workspace layout (16B-aligned chunks)
    unsigned short* keysbf = (unsigned short*)d_ws;      // 1600x512 bf16
    float* sc = (float*)(keysbf + 819200);               // 1024x256 fp32
    float* P  = sc + 262144;                             // 1600x512 fp32
    unsigned short* qh  = (unsigned short*)(P + 819200); // 1024x512 bf16
    unsigned short* wot = qh + 524288;                   // WoT 512x1024 bf16

    k_stage1<<<968, 256, 0, stream>>>(query, src, trg, Wq, Ws, Wo, bq,
                                      qh, keysbf, wot);
    k_stage2<<<584, 256, 0, stream>>>(query, qh, keysbf, wot, bo, sc, P, out);
    k_stageD<<<dim3(16, 8, 4), 256, 0, stream>>>(sc, P, out);
}

// Round 9
// 142.548 us; speedup vs baseline: 1.0762x; 1.0762x over previous
//
#include <hip/hip_runtime.h>
#include <math.h>

// DynamicAttention1 — round 19b: RESUBMIT (container failed twice, no data).
// Split-K x4 on keys GEMM (occupancy fix).
// R18 counters: k_stage1 53-60us @ 12.5% occupancy — after light blocks drain,
// 200 keys blocks run at <1 block/CU, 32 serial latency-exposed iters each
// (~1.4us/iter: 2 barriers + 16-dword B-gather, zero TLP). Fix: split-K x4 ->
// 800 blocks x 8 iters (K-chunks of 512): ~3.1 keys-blocks/CU (TLP hides the
// gather) AND 4x shorter serial path. Epilogue = R12-proven fp32
// unsafeAtomicAdd onto hipMemsetAsync-zeroed keys; scgemm/Pgemm consume fp32
// keys via cvt8 (R17 proved in-loop cvt is latency-hidden).
//   S1: keys 800 (splitKx4, 8it) + qh 256 (8it) + WoT transpose 512
//   S2: scgemm 128 + Pgemm 200 + out_left 256   [all 8-iter]
//   S3: softmax + wP -> atomic out (512 blk)
// keys UNBIASED everywhere (bs cancels in score diff and in ctx); bq/bo kept.

typedef __attribute__((ext_vector_type(8))) short s16x8;
typedef __attribute__((ext_vector_type(4))) float f32x4;

__device__ __forceinline__ unsigned short f2bf(float f) {
    unsigned int u = __float_as_uint(f);
    return (unsigned short)((u + 0x7fffu + ((u >> 16) & 1u)) >> 16);  // RNE
}

__device__ __forceinline__ s16x8 cvt8(const float* p) {
    float4 u = *(const float4*)p, w = *(const float4*)(p + 4);
    s16x8 o;
    o[0] = (short)f2bf(u.x); o[1] = (short)f2bf(u.y);
    o[2] = (short)f2bf(u.z); o[3] = (short)f2bf(u.w);
    o[4] = (short)f2bf(w.x); o[5] = (short)f2bf(w.y);
    o[6] = (short)f2bf(w.z); o[7] = (short)f2bf(w.w);
    return o;
}

// ---------------- keys GEMM: split-K x4, A raw fp32, B raw Ws (gather) ------
// 64x64 tile, 4 waves 2x2; K-chunk 512 (8 iters), fp32 atomic epilogue.
__device__ __forceinline__ void gemm64_keys(
    const float* __restrict__ src, const float* __restrict__ trg,
    const float* __restrict__ Ws, float* __restrict__ Kf,
    int m0, int n0, int kbase, unsigned short* As, unsigned short* Bs) {
    const int t = threadIdx.x;
    const int lane = t & 63, wid = t >> 6;
    const int wm = (wid & 1) * 32, wn = (wid >> 1) * 32;
    const int lr = lane & 15, lq = lane >> 4;
    const int r = t >> 3, c8 = (t & 7) * 8;        // A staging coords
    const int nrow = t >> 2, kc16 = (t & 3) * 16;  // B staging coords

    const int ra_row = m0 + r, rb_row = m0 + r + 32;
    const float* arp = (ra_row < 800) ? (src + (size_t)ra_row * 2048)
                                      : (trg + (size_t)(ra_row - 800) * 2048);
    const float* brp = (rb_row < 800) ? (src + (size_t)rb_row * 2048)
                                      : (trg + (size_t)(rb_row - 800) * 2048);

    s16x8 ra0, ra1;
    float bw[16];
#define LDK(kt)                                                              \
    ra0 = cvt8(arp + (kt) + c8);                                             \
    ra1 = cvt8(brp + (kt) + c8);                                             \
    _Pragma("unroll")                                                        \
    for (int j = 0; j < 16; j++)                                             \
        bw[j] = Ws[(size_t)((kt) + kc16 + j) * 512 + n0 + nrow];

    f32x4 acc[2][2] = {};
    LDK(kbase);
    for (int it = 0; it < 8; it++) {
        __syncthreads();
        *(s16x8*)&As[r * 72 + c8]        = ra0;
        *(s16x8*)&As[(r + 32) * 72 + c8] = ra1;
        {   // B: cvt 16 fp32 -> 2 x b128 transposed writes (Bs[n][k])
            s16x8 bb0, bb1;
#pragma unroll
            for (int j = 0; j < 8; j++) {
                bb0[j] = (short)f2bf(bw[j]);
                bb1[j] = (short)f2bf(bw[8 + j]);
            }
            *(s16x8*)&Bs[nrow * 72 + kc16]     = bb0;
            *(s16x8*)&Bs[nrow * 72 + kc16 + 8] = bb1;
        }
        __syncthreads();
        if (it < 7) { LDK(kbase + (it + 1) * 64); }  // prefetch
#pragma unroll
        for (int s = 0; s < 2; s++) {
            s16x8 a0 = *(const s16x8*)&As[(wm + lr) * 72      + s * 32 + lq * 8];
            s16x8 a1 = *(const s16x8*)&As[(wm + 16 + lr) * 72 + s * 32 + lq * 8];
            s16x8 b0 = *(const s16x8*)&Bs[(wn + lr) * 72      + s * 32 + lq * 8];
            s16x8 b1 = *(const s16x8*)&Bs[(wn + 16 + lr) * 72 + s * 32 + lq * 8];
            acc[0][0] = __builtin_amdgcn_mfma_f32_16x16x32_bf16(a0, b0, acc[0][0], 0, 0, 0);
            acc[0][1] = __builtin_amdgcn_mfma_f32_16x16x32_bf16(a0, b1, acc[0][1], 0, 0, 0);
            acc[1][0] = __builtin_amdgcn_mfma_f32_16x16x32_bf16(a1, b0, acc[1][0], 0, 0, 0);
            acc[1][1] = __builtin_amdgcn_mfma_f32_16x16x32_bf16(a1, b1, acc[1][1], 0, 0, 0);
        }
    }
#undef LDK
#pragma unroll
    for (int i = 0; i < 2; i++)
#pragma unroll
        for (int j = 0; j < 2; j++) {
            const int col = n0 + wn + j * 16 + lr;      // C/D: col=lane&15
            const int row = m0 + wm + i * 16 + lq * 4;  //      row=quad*4+reg
#pragma unroll
            for (int rr = 0; rr < 4; rr++)
                unsafeAtomicAdd(&Kf[(size_t)(row + rr) * 512 + col],
                                acc[i][j][rr]);
        }
}

// ---------------- qh GEMM: A=raw query, B=raw Wq (write-transpose) ----------
// 32x64 tile, 4 waves, K=512 (8 iters), bf16+bias epilogue.
__device__ __forceinline__ void gemm32_rawB(
    const float* __restrict__ A, const float* __restrict__ W,
    const float* __restrict__ bias, unsigned short* __restrict__ C,
    int m0, int n0, unsigned short* As, unsigned short* Bs) {
    const int t = threadIdx.x;
    const int lane = t & 63, wid = t >> 6;
    const int wm = (wid & 1) * 16, wn = (wid >> 1) * 32;
    const int lr = lane & 15, lq = lane >> 4;
    const int r = t >> 3, c8 = (t & 7) * 8;
    const int nrow = t >> 2, kc16 = (t & 3) * 16;

    s16x8 ra;
    float bw[16];
#define LDQ(kt)                                                              \
    ra = cvt8(A + (size_t)(m0 + r) * 512 + (kt) + c8);                       \
    _Pragma("unroll")                                                        \
    for (int j = 0; j < 16; j++)                                             \
        bw[j] = W[(size_t)((kt) + kc16 + j) * 512 + n0 + nrow];

    f32x4 acc[2] = {};
    LDQ(0);
    for (int it = 0; it < 8; it++) {
        __syncthreads();
        *(s16x8*)&As[r * 72 + c8] = ra;
        {
            s16x8 bb0, bb1;
#pragma unroll
            for (int j = 0; j < 8; j++) {
                bb0[j] = (short)f2bf(bw[j]);
                bb1[j] = (short)f2bf(bw[8 + j]);
            }
            *(s16x8*)&Bs[nrow * 72 + kc16]     = bb0;
            *(s16x8*)&Bs[nrow * 72 + kc16 + 8] = bb1;
        }
        __syncthreads();
        if (it < 7) { LDQ((it + 1) * 64); }  // prefetch
#pragma unroll
        for (int s = 0; s < 2; s++) {
            s16x8 a0 = *(const s16x8*)&As[(wm + lr) * 72      + s * 32 + lq * 8];
            s16x8 b0 = *(const s16x8*)&Bs[(wn + lr) * 72      + s * 32 + lq * 8];
            s16x8 b1 = *(const s16x8*)&Bs[(wn + 16 + lr) * 72 + s * 32 + lq * 8];
            acc[0] = __builtin_amdgcn_mfma_f32_16x16x32_bf16(a0, b0, acc[0], 0, 0, 0);
            acc[1] = __builtin_amdgcn_mfma_f32_16x16x32_bf16(a0, b1, acc[1], 0, 0, 0);
        }
    }
#undef LDQ
#pragma unroll
    for (int j = 0; j < 2; j++) {
        const int col = n0 + wn + j * 16 + lr;
        const int row = m0 + wm + lq * 4;
        const float bv = bias[col];
#pragma unroll
        for (int rr = 0; rr < 4; rr++)
            C[(size_t)(row + rr) * 512 + col] = f2bf(acc[j][rr] + bv);
    }
}

// ---------------- out_left GEMM: A=raw query, BT=wot bf16, fp32+bias --------
__device__ __forceinline__ void gemm32_cvtA(
    const float* __restrict__ A, const unsigned short* __restrict__ BT,
    const float* __restrict__ bias, float* __restrict__ C,
    int m0, int n0, int KB, unsigned short* As, unsigned short* Bs) {
    const int t = threadIdx.x;
    const int lane = t & 63, wid = t >> 6;
    const int wm = (wid & 1) * 16, wn = (wid >> 1) * 32;
    const int lr = lane & 15, lq = lane >> 4;
    const int r = t >> 3, c8 = (t & 7) * 8;

    s16x8 ra, rb0, rb1;
#define LD32(kt)                                                            \
    ra  = cvt8(A + (size_t)(m0 + r) * 512 + (kt) + c8);                     \
    rb0 = *(const s16x8*)(BT + (size_t)(n0 + r)      * KB + (kt) + c8);     \
    rb1 = *(const s16x8*)(BT + (size_t)(n0 + r + 32) * KB + (kt) + c8);

    f32x4 acc[2] = {};
    LD32(0);
    for (int it = 0; it < 8; it++) {
        __syncthreads();
        *(s16x8*)&As[r * 72 + c8]        = ra;
        *(s16x8*)&Bs[r * 72 + c8]        = rb0;
        *(s16x8*)&Bs[(r + 32) * 72 + c8] = rb1;
        __syncthreads();
        if (it < 7) { LD32((it + 1) * 64); }  // prefetch
#pragma unroll
        for (int s = 0; s < 2; s++) {
            s16x8 a0 = *(const s16x8*)&As[(wm + lr) * 72      + s * 32 + lq * 8];
            s16x8 b0 = *(const s16x8*)&Bs[(wn + lr) * 72      + s * 32 + lq * 8];
            s16x8 b1 = *(const s16x8*)&Bs[(wn + 16 + lr) * 72 + s * 32 + lq * 8];
            acc[0] = __builtin_amdgcn_mfma_f32_16x16x32_bf16(a0, b0, acc[0], 0, 0, 0);
            acc[1] = __builtin_amdgcn_mfma_f32_16x16x32_bf16(a0, b1, acc[1], 0, 0, 0);
        }
    }
#undef LD32
#pragma unroll
    for (int j = 0; j < 2; j++) {
        const int col = n0 + wn + j * 16 + lr;
        const int row = m0 + wm + lq * 4;
        const float bv = bias[col];
#pragma unroll
        for (int rr = 0; rr < 4; rr++)
            C[(size_t)(row + rr) * 512 + col] = acc[j][rr] + bv;
    }
}

// ---------------- P GEMM: P = keys(fp32,cvt) @ WoBot (wot+512), fp32 store --
__device__ __forceinline__ void gemm64_P(
    const float* __restrict__ Kf, const unsigned short* __restrict__ wotBot,
    float* __restrict__ P, int m0, int n0, unsigned short* As,
    unsigned short* Bs) {
    const int t = threadIdx.x;
    const int lane = t & 63, wid = t >> 6;
    const int wm = (wid & 1) * 32, wn = (wid >> 1) * 32;
    const int lr = lane & 15, lq = lane >> 4;
    const int r = t >> 3, c8 = (t & 7) * 8;

    s16x8 ra0, ra1, rb0, rb1;
#define LDP(kt)                                                               \
    ra0 = cvt8(Kf + (size_t)(m0 + r)      * 512 + (kt) + c8);                 \
    ra1 = cvt8(Kf + (size_t)(m0 + r + 32) * 512 + (kt) + c8);                 \
    rb0 = *(const s16x8*)(wotBot + (size_t)(n0 + r)      * 1024 + (kt) + c8); \
    rb1 = *(const s16x8*)(wotBot + (size_t)(n0 + r + 32) * 1024 + (kt) + c8);

    f32x4 acc[2][2] = {};
    LDP(0);
    for (int it = 0; it < 8; it++) {
        __syncthreads();
        *(s16x8*)&As[r * 72 + c8]        = ra0;
        *(s16x8*)&As[(r + 32) * 72 + c8] = ra1;
        *(s16x8*)&Bs[r * 72 + c8]        = rb0;
        *(s16x8*)&Bs[(r + 32) * 72 + c8] = rb1;
        __syncthreads();
        if (it < 7) { LDP((it + 1) * 64); }  // prefetch
#pragma unroll
        for (int s = 0; s < 2; s++) {
            s16x8 a0 = *(const s16x8*)&As[(wm + lr) * 72      + s * 32 + lq * 8];
            s16x8 a1 = *(const s16x8*)&As[(wm + 16 + lr) * 72 + s * 32 + lq * 8];
            s16x8 b0 = *(const s16x8*)&Bs[(wn + lr) * 72      + s * 32 + lq * 8];
            s16x8 b1 = *(const s16x8*)&Bs[(wn + 16 + lr) * 72 + s * 32 + lq * 8];
            acc[0][0] = __builtin_amdgcn_mfma_f32_16x16x32_bf16(a0, b0, acc[0][0], 0, 0, 0);
            acc[0][1] = __builtin_amdgcn_mfma_f32_16x16x32_bf16(a0, b1, acc[0][1], 0, 0, 0);
            acc[1][0] = __builtin_amdgcn_mfma_f32_16x16x32_bf16(a1, b0, acc[1][0], 0, 0, 0);
            acc[1][1] = __builtin_amdgcn_mfma_f32_16x16x32_bf16(a1, b1, acc[1][1], 0, 0, 0);
        }
    }
#undef LDP
#pragma unroll
    for (int i = 0; i < 2; i++)
#pragma unroll
        for (int j = 0; j < 2; j++) {
            const int col = n0 + wn + j * 16 + lr;
            const int row = m0 + wm + i * 16 + lq * 4;
#pragma unroll
            for (int rr = 0; rr < 4; rr++)
                P[(size_t)(row + rr) * 512 + col] = acc[i][j][rr];
        }
}

// ---------------- S1: keys (800 splitKx4) + qh (256) + WoT transpose (512) --
__global__ __launch_bounds__(256) void k_stage1(
    const float* __restrict__ query, const float* __restrict__ src,
    const float* __restrict__ trg, const float* __restrict__ Wq,
    const float* __restrict__ Ws, const float* __restrict__ Wo,
    const float* __restrict__ bq, unsigned short* __restrict__ qh,
    float* __restrict__ keys, unsigned short* __restrict__ wot) {
    __shared__ __align__(16) unsigned short As[64 * 72];
    __shared__ __align__(16) unsigned short Bs[64 * 72];
    const int bid = blockIdx.x, t = threadIdx.x;

    if (bid < 800) {
        const int c = bid / 200, rem = bid % 200;
        gemm64_keys(src, trg, Ws, keys, (rem >> 3) * 64, (rem & 7) * 64,
                    c * 512, As, Bs);
    } else if (bid < 1056) {
        const int rr = bid - 800;
        gemm32_rawB(query, Wq, bq, qh, (rr >> 3) * 32, (rr & 7) * 64, As, Bs);
    } else {
        // WoT transpose: Wo[1024][512] -> wot[n=512][k=1024], 32x32 tiles
        float (*tile)[33] = (float(*)[33])As;   // 4.2KB alias over As
        const int id2 = bid - 1056;             // 0..511
        const int tk = id2 >> 4, tn = id2 & 15;
        const int row = t >> 3, c4 = (t & 7) * 4;
        float4 v = *(const float4*)(Wo + (size_t)(tk * 32 + row) * 512 + tn * 32 + c4);
        tile[row][c4 + 0] = v.x; tile[row][c4 + 1] = v.y;
        tile[row][c4 + 2] = v.z; tile[row][c4 + 3] = v.w;
        __syncthreads();
        ushort4 o = make_ushort4(f2bf(tile[c4 + 0][row]), f2bf(tile[c4 + 1][row]),
                                 f2bf(tile[c4 + 2][row]), f2bf(tile[c4 + 3][row]));
        *(ushort4*)(wot + (size_t)(tn * 32 + row) * 1024 + tk * 32 + c4) = o;
    }
}

// ---------------- S2: scgemm (128) + Pgemm (200) + out_left (256) -----------
__global__ __launch_bounds__(256) void k_stage2(
    const float* __restrict__ query, const unsigned short* __restrict__ qh,
    const float* __restrict__ keys, const unsigned short* __restrict__ wot,
    const float* __restrict__ bo, float* __restrict__ sc,
    float* __restrict__ P, float* __restrict__ out) {
    __shared__ __align__(16) unsigned short As[64 * 72];
    __shared__ __align__(16) unsigned short Bs[64 * 72];
    const int bid = blockIdx.x;
    const int t = threadIdx.x;

    if (bid >= 328) {                       // ---- out_left ----
        const int rr = bid - 328;
        gemm32_cvtA(query, wot, bo, out, (rr >> 3) * 32, (rr & 7) * 64, 1024,
                    As, Bs);
        return;
    }
    if (bid >= 128) {                       // ---- Pgemm ----
        const int rem = bid - 128;
        gemm64_P(keys, wot + 512, P, (rem >> 3) * 64, (rem & 7) * 64, As, Bs);
        return;
    }

    // ---- scgemm: sc cols 0..99 = qs/32, 128..227 = -qt/32 ----
    const int mt = bid >> 2, nt = bid & 3;
    const int m0 = mt * 32, b = mt >> 2, n0 = nt * 64;
    const int lane = t & 63, wid = t >> 6;
    const int wm = (wid & 1) * 16, wn = (wid >> 1) * 32;
    const int lr = lane & 15, lq = lane >> 4;
    const int r = t >> 3, c8 = (t & 7) * 8;

    const int nA = n0 + r, nB = n0 + r + 32;
    int kr0 = (nA < 128) ? (b * 100 + nA) : (800 + b * 100 + (nA - 128));
    int kr1 = (nB < 128) ? (b * 100 + nB) : (800 + b * 100 + (nB - 128));
    kr0 = kr0 > 1599 ? 1599 : kr0;
    kr1 = kr1 > 1599 ? 1599 : kr1;

    s16x8 ra, rb0, rb1;
#define LDSC(kt)                                                        \
    ra  = *(const s16x8*)(qh + (size_t)(m0 + r) * 512 + (kt) + c8);     \
    rb0 = cvt8(keys + (size_t)kr0 * 512 + (kt) + c8);                   \
    rb1 = cvt8(keys + (size_t)kr1 * 512 + (kt) + c8);

    f32x4 acc[2] = {};
    LDSC(0);
    for (int it = 0; it < 8; it++) {
        __syncthreads();
        *(s16x8*)&As[r * 72 + c8]        = ra;
        *(s16x8*)&Bs[r * 72 + c8]        = rb0;
        *(s16x8*)&Bs[(r + 32) * 72 + c8] = rb1;
        __syncthreads();
        if (it < 7) { LDSC((it + 1) * 64); }
#pragma unroll
        for (int s = 0; s < 2; s++) {
            s16x8 a0 = *(const s16x8*)&As[(wm + lr) * 72      + s * 32 + lq * 8];
            s16x8 b0 = *(const s16x8*)&Bs[(wn + lr) * 72      + s * 32 + lq * 8];
            s16x8 b1 = *(const s16x8*)&Bs[(wn + 16 + lr) * 72 + s * 32 + lq * 8];
            acc[0] = __builtin_amdgcn_mfma_f32_16x16x32_bf16(a0, b0, acc[0], 0, 0, 0);
            acc[1] = __builtin_amdgcn_mfma_f32_16x16x32_bf16(a0, b1, acc[1], 0, 0, 0);
        }
    }
#undef LDSC
#pragma unroll
    for (int j = 0; j < 2; j++) {
        const int col = n0 + wn + j * 16 + lr;
        const int row = m0 + wm + lq * 4;
        const float scale = (col >= 128) ? -(1.0f / 32.0f) : (1.0f / 32.0f);
#pragma unroll
        for (int rr = 0; rr < 4; rr++)
            sc[(size_t)(row + rr) * 256 + col] = acc[j][rr] * scale;
    }
}

// ---------------- S3: softmax + wP GEMM -> atomic into out ------------------
// grid (16 n-tiles, 8 b, 4 l-tiles) = 512 blocks of 32(l) x 32(n), K=200.
__global__ __launch_bounds__(256) void k_stageD(
    const float* __restrict__ sc, const float* __restrict__ P,
    float* __restrict__ out) {
    __shared__ float wbuf[200 * 33];     // [st][l], pad 33
    __shared__ float Bs[40 * 32];        // [k][n]

    const int t = threadIdx.x;
    const int b = blockIdx.y;
    const int n0 = blockIdx.x * 32;
    const int l0 = blockIdx.z * 32;
    const int wave = t >> 6, lane = t & 63;

    // ---- softmax: each wave handles 8 rows; lane covers cols lane*4..+3 ----
    for (int i = 0; i < 8; i++) {
        const int li = wave * 8 + i;                  // 0..31
        const float4 v = *(const float4*)(
            sc + (size_t)(b * 128 + l0 + li) * 256 + lane * 4);
        const float vv[4] = {v.x, v.y, v.z, v.w};
        const int c0 = lane * 4;
        float mS = -1e30f, mT = -1e30f;
#pragma unroll
        for (int j = 0; j < 4; j++) {
            const int col = c0 + j;
            if (col < 100) mS = fmaxf(mS, vv[j]);
            if (col >= 128 && col < 228) mT = fmaxf(mT, vv[j]);
        }
#pragma unroll
        for (int off = 32; off > 0; off >>= 1) {
            mS = fmaxf(mS, __shfl_xor(mS, off));
            mT = fmaxf(mT, __shfl_xor(mT, off));
        }
        float eS[4], eT[4], sS = 0.f, sT = 0.f;
#pragma unroll
        for (int j = 0; j < 4; j++) {
            const int col = c0 + j;
            eS[j] = (col < 100) ? __expf(vv[j] - mS) : 0.f;
            eT[j] = (col >= 128 && col < 228) ? __expf(vv[j] - mT) : 0.f;
            sS += eS[j]; sT += eT[j];
        }
#pragma unroll
        for (int off = 32; off > 0; off >>= 1) {
            sS += __shfl_xor(sS, off);
            sT += __shfl_xor(sT, off);
        }
        const float iS = 1.f / sS, iT = 1.f / sT;
#pragma unroll
        for (int j = 0; j < 4; j++) {
            const int col = c0 + j;
            if (col < 100) wbuf[col * 33 + li] = eS[j] * iS;
            if (col >= 128 && col < 228)
                wbuf[(100 + col - 128) * 33 + li] = eT[j] * iT;
        }
    }
    __syncthreads();

    // ---- GEMM: acc[l][n] += w[st][l] * (+P_s|-P_t)[st][n] ------------------
    const int tx = t & 7, ty = t >> 3;   // tx: n/4, ty: l
    float rB[5];
    auto loadB = [&](int kbase) {
#pragma unroll
        for (int e = 0; e < 5; e++) {
            const int idx = t + e * 256;
            const int k = idx >> 5, j = idx & 31;
            const int kk = kbase + k;
            rB[e] = (kk < 100)
                ?  P[(size_t)(b * 100 + kk) * 512 + n0 + j]
                : -P[(size_t)(800 + b * 100 + (kk - 100)) * 512 + n0 + j];
        }
    };

    float acc[4] = {};
    loadB(0);
    for (int c5 = 0; c5 < 5; c5++) {
        __syncthreads();
#pragma unroll
        for (int e = 0; e < 5; e++) {
            const int idx = t + e * 256;
            Bs[idx] = rB[e];
        }
        __syncthreads();
        if (c5 < 4) loadB((c5 + 1) * 40);          // prefetch next chunk
#pragma unroll 8
        for (int k = 0; k < 40; k++) {
            const float ar = wbuf[(c5 * 40 + k) * 33 + ty];
            float br[4];
            *(float4*)br = *(const float4*)&Bs[k * 32 + tx * 4];
#pragma unroll
            for (int j = 0; j < 4; j++) acc[j] = fmaf(ar, br[j], acc[j]);
        }
    }

    const float s2 = 0.70710678118654752f;  // 1/sqrt(2)
    const int m = b * 128 + l0 + ty;
#pragma unroll
    for (int j = 0; j < 4; j++)
        unsafeAtomicAdd(&out[(size_t)m * 512 + n0 + tx * 4 + j], acc[j] * s2);
}

// ---------------- launch ----------------------------------------------------

extern "C" void kernel_launch(void* const* d_in, const int* in_sizes, int n_in,
                              void* d_out, int out_size, void* d_ws, size_t ws_size,
                              hipStream_t stream) {
    const float* query = (const float*)d_in[0];
    const float* src   = (const float*)d_in[1];
    const float* trg   = (const float*)d_in[2];
    const float* Wq    = (const float*)d_in[3];
    const float* bq    = (const float*)d_in[4];
    const float* Ws    = (const float*)d_in[5];
    const float* Wo    = (const float*)d_in[7];
    const float* bo    = (const float*)d_in[8];
    float* out = (float*)d_out;

    // workspace layout (16B-aligned chunks)
    float* keys = (float*)d_ws;                          // 1600x512 fp32
    float* sc   = keys + 819200;                         // 1024x256 fp32
    float* P    = sc + 262144;                           // 1600x512 fp32
    unsigned short* qh  = (unsigned short*)(P + 819200); // 1024x512 bf16
    unsigned short* wot = qh + 524288;                   // WoT 512x1024 bf16

    hipMemsetAsync(keys, 0, 1600 * 512 * sizeof(float), stream);
    k_stage1<<<1568, 256, 0, stream>>>(query, src, trg, Wq, Ws, Wo, bq,
                                       qh, keys, wot);
    k_stage2<<<584, 256, 0, stream>>>(query, qh, keys, wot, bo, sc, P, out);
    k_stageD<<<dim3(16, 8, 4), 256, 0, stream>>>(sc, P, out);
}

// Round 11
// 136.652 us; speedup vs baseline: 1.1226x; 1.0431x over previous
//
#include <hip/hip_runtime.h>
#include <math.h>

// DynamicAttention1 — round 20b: RESUBMIT (acquisition timeout, no data).
// Recombine proven-best pieces.
// Evidence: R17 (pre-transposed B, cheap iters) 133.4; R18 (raw-B gather)
// stage1 53-60us — gather ~2x per-iter cost; R19 (splitKx4 + memset boundary)
// 142.5. Fix both: restore LEAN prep (WsT/WqT transposes + keys zero ONLY),
// keys splitKx4 with CHEAP bf16-BT iterations (800 blk x 8 it), WoT transpose
// rides in stageB (consumed only in stageC), out_left moves to stageC.
//   prep:   WqT 256 + WsT 1024 + keys-zero 800            = 2080 blk
//   stageB: keys splitKx4 800 (8it, bf16 BT) + qh 256 + WoT 512 = 1568 blk
//   stageC: scgemm 128 + Pgemm 200 + out_left 256          = 584 blk
//   stageD: softmax + wP -> atomic out                     = 512 blk
// keys fp32 atomic-accumulated (R12-proven); consumers cvt8 (R17: free).
// keys UNBIASED everywhere (bs cancels in score diff and in ctx).
// Prediction: ~110-120us total; stageB ~22-28us.

typedef __attribute__((ext_vector_type(8))) short s16x8;
typedef __attribute__((ext_vector_type(4))) float f32x4;

__device__ __forceinline__ unsigned short f2bf(float f) {
    unsigned int u = __float_as_uint(f);
    return (unsigned short)((u + 0x7fffu + ((u >> 16) & 1u)) >> 16);  // RNE
}

__device__ __forceinline__ s16x8 cvt8(const float* p) {
    float4 u = *(const float4*)p, w = *(const float4*)(p + 4);
    s16x8 o;
    o[0] = (short)f2bf(u.x); o[1] = (short)f2bf(u.y);
    o[2] = (short)f2bf(u.z); o[3] = (short)f2bf(u.w);
    o[4] = (short)f2bf(w.x); o[5] = (short)f2bf(w.y);
    o[6] = (short)f2bf(w.z); o[7] = (short)f2bf(w.w);
    return o;
}

// ---------------- prep: WqT/WsT transpose-casts + keys zero -----------------
__global__ __launch_bounds__(256) void k_prep(
    const float* __restrict__ Wq, const float* __restrict__ Ws,
    unsigned short* __restrict__ WqT, unsigned short* __restrict__ WsT,
    float* __restrict__ keys) {
    __shared__ float tile[32][33];
    const int id = blockIdx.x, t = threadIdx.x;

    if (id < 1280) {                        // weight transpose-cast, 32x32 tiles
        const float* W; unsigned short* O; int K, tk, tn;
        if (id < 256) { W = Wq; O = WqT; K = 512;  tk = id >> 4;         tn = id & 15; }
        else          { W = Ws; O = WsT; K = 2048; tk = (id - 256) >> 4; tn = (id - 256) & 15; }
        const int row = t >> 3, c4 = (t & 7) * 4;
        float4 v = *(const float4*)(W + (size_t)(tk * 32 + row) * 512 + tn * 32 + c4);
        tile[row][c4 + 0] = v.x; tile[row][c4 + 1] = v.y;
        tile[row][c4 + 2] = v.z; tile[row][c4 + 3] = v.w;
        __syncthreads();
        ushort4 o = make_ushort4(f2bf(tile[c4 + 0][row]), f2bf(tile[c4 + 1][row]),
                                 f2bf(tile[c4 + 2][row]), f2bf(tile[c4 + 3][row]));
        *(ushort4*)(O + (size_t)(tn * 32 + row) * K + tk * 32 + c4) = o;
    } else {                                // keys = 0 (split-K base)
        const int f = ((id - 1280) * 256 + t) * 4;
        *(float4*)(keys + f) = make_float4(0.f, 0.f, 0.f, 0.f);
    }
}

// ---------------- keys GEMM: splitKx4, A raw fp32, BT=wst bf16 (cheap) ------
// 64x64 tile, 4 waves 2x2; K-chunk 512 (8 iters), fp32 atomic epilogue.
__device__ __forceinline__ void gemm64_keys(
    const float* __restrict__ src, const float* __restrict__ trg,
    const unsigned short* __restrict__ BT, float* __restrict__ Kf,
    int m0, int n0, int kbase, unsigned short* As, unsigned short* Bs) {
    const int t = threadIdx.x;
    const int lane = t & 63, wid = t >> 6;
    const int wm = (wid & 1) * 32, wn = (wid >> 1) * 32;
    const int lr = lane & 15, lq = lane >> 4;
    const int r = t >> 3, c8 = (t & 7) * 8;

    const int ra_row = m0 + r, rb_row = m0 + r + 32;
    const float* arp = (ra_row < 800) ? (src + (size_t)ra_row * 2048)
                                      : (trg + (size_t)(ra_row - 800) * 2048);
    const float* brp = (rb_row < 800) ? (src + (size_t)rb_row * 2048)
                                      : (trg + (size_t)(rb_row - 800) * 2048);

    s16x8 ra0, ra1, rb0, rb1;
#define LDK(kt)                                                            \
    ra0 = cvt8(arp + (kt) + c8);                                           \
    ra1 = cvt8(brp + (kt) + c8);                                           \
    rb0 = *(const s16x8*)(BT + (size_t)(n0 + r)      * 2048 + (kt) + c8);  \
    rb1 = *(const s16x8*)(BT + (size_t)(n0 + r + 32) * 2048 + (kt) + c8);

    f32x4 acc[2][2] = {};
    LDK(kbase);
    for (int it = 0; it < 8; it++) {
        __syncthreads();
        *(s16x8*)&As[r * 72 + c8]        = ra0;
        *(s16x8*)&As[(r + 32) * 72 + c8] = ra1;
        *(s16x8*)&Bs[r * 72 + c8]        = rb0;
        *(s16x8*)&Bs[(r + 32) * 72 + c8] = rb1;
        __syncthreads();
        if (it < 7) { LDK(kbase + (it + 1) * 64); }  // prefetch
#pragma unroll
        for (int s = 0; s < 2; s++) {
            s16x8 a0 = *(const s16x8*)&As[(wm + lr) * 72      + s * 32 + lq * 8];
            s16x8 a1 = *(const s16x8*)&As[(wm + 16 + lr) * 72 + s * 32 + lq * 8];
            s16x8 b0 = *(const s16x8*)&Bs[(wn + lr) * 72      + s * 32 + lq * 8];
            s16x8 b1 = *(const s16x8*)&Bs[(wn + 16 + lr) * 72 + s * 32 + lq * 8];
            acc[0][0] = __builtin_amdgcn_mfma_f32_16x16x32_bf16(a0, b0, acc[0][0], 0, 0, 0);
            acc[0][1] = __builtin_amdgcn_mfma_f32_16x16x32_bf16(a0, b1, acc[0][1], 0, 0, 0);
            acc[1][0] = __builtin_amdgcn_mfma_f32_16x16x32_bf16(a1, b0, acc[1][0], 0, 0, 0);
            acc[1][1] = __builtin_amdgcn_mfma_f32_16x16x32_bf16(a1, b1, acc[1][1], 0, 0, 0);
        }
    }
#undef LDK
#pragma unroll
    for (int i = 0; i < 2; i++)
#pragma unroll
        for (int j = 0; j < 2; j++) {
            const int col = n0 + wn + j * 16 + lr;      // C/D: col=lane&15
            const int row = m0 + wm + i * 16 + lq * 4;  //      row=quad*4+reg
#pragma unroll
            for (int rr = 0; rr < 4; rr++)
                unsafeAtomicAdd(&Kf[(size_t)(row + rr) * 512 + col],
                                acc[i][j][rr]);
        }
}

// 32x64 tile, 4 waves. A fp32 (cvt in staging), BT bf16. MODE 0: fp32+bias,
// 2: bf16+bias.
template <int MODE>
__device__ __forceinline__ void gemm32(
    const float* __restrict__ A, const unsigned short* __restrict__ BT,
    const float* __restrict__ bias, void* __restrict__ Cv,
    int m0, int n0, int KA, int KB, int N, int kiters,
    unsigned short* As, unsigned short* Bs) {
    const int t = threadIdx.x;
    const int lane = t & 63, wid = t >> 6;
    const int wm = (wid & 1) * 16, wn = (wid >> 1) * 32;
    const int lr = lane & 15, lq = lane >> 4;
    const int r = t >> 3, c8 = (t & 7) * 8;

    s16x8 ra, rb0, rb1;
#define LD32(kt)                                                            \
    ra  = cvt8(A + (size_t)(m0 + r) * KA + (kt) + c8);                      \
    rb0 = *(const s16x8*)(BT + (size_t)(n0 + r)      * KB + (kt) + c8);     \
    rb1 = *(const s16x8*)(BT + (size_t)(n0 + r + 32) * KB + (kt) + c8);

    f32x4 acc[2] = {};
    LD32(0);
    for (int it = 0; it < kiters; it++) {
        __syncthreads();
        *(s16x8*)&As[r * 72 + c8]        = ra;
        *(s16x8*)&Bs[r * 72 + c8]        = rb0;
        *(s16x8*)&Bs[(r + 32) * 72 + c8] = rb1;
        __syncthreads();
        if (it + 1 < kiters) { LD32((it + 1) * 64); }  // prefetch
#pragma unroll
        for (int s = 0; s < 2; s++) {
            s16x8 a0 = *(const s16x8*)&As[(wm + lr) * 72      + s * 32 + lq * 8];
            s16x8 b0 = *(const s16x8*)&Bs[(wn + lr) * 72      + s * 32 + lq * 8];
            s16x8 b1 = *(const s16x8*)&Bs[(wn + 16 + lr) * 72 + s * 32 + lq * 8];
            acc[0] = __builtin_amdgcn_mfma_f32_16x16x32_bf16(a0, b0, acc[0], 0, 0, 0);
            acc[1] = __builtin_amdgcn_mfma_f32_16x16x32_bf16(a0, b1, acc[1], 0, 0, 0);
        }
    }
#undef LD32
#pragma unroll
    for (int j = 0; j < 2; j++) {
        const int col = n0 + wn + j * 16 + lr;
        const int row = m0 + wm + lq * 4;
        const float bv = bias[col];
        if (MODE == 0) {
            float* C = (float*)Cv;
#pragma unroll
            for (int rr = 0; rr < 4; rr++)
                C[(size_t)(row + rr) * N + col] = acc[j][rr] + bv;
        } else {
            unsigned short* C = (unsigned short*)Cv;
#pragma unroll
            for (int rr = 0; rr < 4; rr++)
                C[(size_t)(row + rr) * N + col] = f2bf(acc[j][rr] + bv);
        }
    }
}

// ---------------- P GEMM: P = keys(fp32,cvt) @ WoBot (wot+512), fp32 store --
__device__ __forceinline__ void gemm64_P(
    const float* __restrict__ Kf, const unsigned short* __restrict__ wotBot,
    float* __restrict__ P, int m0, int n0, unsigned short* As,
    unsigned short* Bs) {
    const int t = threadIdx.x;
    const int lane = t & 63, wid = t >> 6;
    const int wm = (wid & 1) * 32, wn = (wid >> 1) * 32;
    const int lr = lane & 15, lq = lane >> 4;
    const int r = t >> 3, c8 = (t & 7) * 8;

    s16x8 ra0, ra1, rb0, rb1;
#define LDP(kt)                                                               \
    ra0 = cvt8(Kf + (size_t)(m0 + r)      * 512 + (kt) + c8);                 \
    ra1 = cvt8(Kf + (size_t)(m0 + r + 32) * 512 + (kt) + c8);                 \
    rb0 = *(const s16x8*)(wotBot + (size_t)(n0 + r)      * 1024 + (kt) + c8); \
    rb1 = *(const s16x8*)(wotBot + (size_t)(n0 + r + 32) * 1024 + (kt) + c8);

    f32x4 acc[2][2] = {};
    LDP(0);
    for (int it = 0; it < 8; it++) {
        __syncthreads();
        *(s16x8*)&As[r * 72 + c8]        = ra0;
        *(s16x8*)&As[(r + 32) * 72 + c8] = ra1;
        *(s16x8*)&Bs[r * 72 + c8]        = rb0;
        *(s16x8*)&Bs[(r + 32) * 72 + c8] = rb1;
        __syncthreads();
        if (it < 7) { LDP((it + 1) * 64); }  // prefetch
#pragma unroll
        for (int s = 0; s < 2; s++) {
            s16x8 a0 = *(const s16x8*)&As[(wm + lr) * 72      + s * 32 + lq * 8];
            s16x8 a1 = *(const s16x8*)&As[(wm + 16 + lr) * 72 + s * 32 + lq * 8];
            s16x8 b0 = *(const s16x8*)&Bs[(wn + lr) * 72      + s * 32 + lq * 8];
            s16x8 b1 = *(const s16x8*)&Bs[(wn + 16 + lr) * 72 + s * 32 + lq * 8];
            acc[0][0] = __builtin_amdgcn_mfma_f32_16x16x32_bf16(a0, b0, acc[0][0], 0, 0, 0);
            acc[0][1] = __builtin_amdgcn_mfma_f32_16x16x32_bf16(a0, b1, acc[0][1], 0, 0, 0);
            acc[1][0] = __builtin_amdgcn_mfma_f32_16x16x32_bf16(a1, b0, acc[1][0], 0, 0, 0);
            acc[1][1] = __builtin_amdgcn_mfma_f32_16x16x32_bf16(a1, b1, acc[1][1], 0, 0, 0);
        }
    }
#undef LDP
#pragma unroll
    for (int i = 0; i < 2; i++)
#pragma unroll
        for (int j = 0; j < 2; j++) {
            const int col = n0 + wn + j * 16 + lr;
            const int row = m0 + wm + i * 16 + lq * 4;
#pragma unroll
            for (int rr = 0; rr < 4; rr++)
                P[(size_t)(row + rr) * 512 + col] = acc[i][j][rr];
        }
}

// ---------------- stageB: keys 800 (splitKx4) + qh 256 + WoT 512 ------------
__global__ __launch_bounds__(256) void k_stageB(
    const float* __restrict__ query, const float* __restrict__ src,
    const float* __restrict__ trg, const unsigned short* __restrict__ wqt,
    const unsigned short* __restrict__ wst, const float* __restrict__ Wo,
    const float* __restrict__ bq, unsigned short* __restrict__ qh,
    float* __restrict__ keys, unsigned short* __restrict__ wot) {
    __shared__ __align__(16) unsigned short As[64 * 72];
    __shared__ __align__(16) unsigned short Bs[64 * 72];
    const int bid = blockIdx.x, t = threadIdx.x;

    if (bid < 800) {
        const int c = bid / 200, rem = bid % 200;
        gemm64_keys(src, trg, wst, keys, (rem >> 3) * 64, (rem & 7) * 64,
                    c * 512, As, Bs);
    } else if (bid < 1056) {
        const int rr = bid - 800;
        gemm32<2>(query, wqt, bq, qh, (rr >> 3) * 32, (rr & 7) * 64,
                  512, 512, 512, 8, As, Bs);
    } else {
        // WoT transpose: Wo[1024][512] -> wot[n=512][k=1024], 32x32 tiles
        float (*tile)[33] = (float(*)[33])As;   // 4.2KB alias over As
        const int id2 = bid - 1056;             // 0..511
        const int tk = id2 >> 4, tn = id2 & 15;
        const int row = t >> 3, c4 = (t & 7) * 4;
        float4 v = *(const float4*)(Wo + (size_t)(tk * 32 + row) * 512 + tn * 32 + c4);
        tile[row][c4 + 0] = v.x; tile[row][c4 + 1] = v.y;
        tile[row][c4 + 2] = v.z; tile[row][c4 + 3] = v.w;
        __syncthreads();
        ushort4 o = make_ushort4(f2bf(tile[c4 + 0][row]), f2bf(tile[c4 + 1][row]),
                                 f2bf(tile[c4 + 2][row]), f2bf(tile[c4 + 3][row]));
        *(ushort4*)(wot + (size_t)(tn * 32 + row) * 1024 + tk * 32 + c4) = o;
    }
}

// ---------------- stageC: scgemm 128 + Pgemm 200 + out_left 256 -------------
__global__ __launch_bounds__(256) void k_stageC(
    const float* __restrict__ query, const unsigned short* __restrict__ qh,
    const float* __restrict__ keys, const unsigned short* __restrict__ wot,
    const float* __restrict__ bo, float* __restrict__ sc,
    float* __restrict__ P, float* __restrict__ out) {
    __shared__ __align__(16) unsigned short As[64 * 72];
    __shared__ __align__(16) unsigned short Bs[64 * 72];
    const int bid = blockIdx.x;
    const int t = threadIdx.x;

    if (bid >= 328) {                       // ---- out_left ----
        const int rr = bid - 328;
        gemm32<0>(query, wot, bo, out, (rr >> 3) * 32, (rr & 7) * 64,
                  512, 1024, 512, 8, As, Bs);
        return;
    }
    if (bid >= 128) {                       // ---- Pgemm ----
        const int rem = bid - 128;
        gemm64_P(keys, wot + 512, P, (rem >> 3) * 64, (rem & 7) * 64, As, Bs);
        return;
    }

    // ---- scgemm: sc cols 0..99 = qs/32, 128..227 = -qt/32 ----
    const int mt = bid >> 2, nt = bid & 3;
    const int m0 = mt * 32, b = mt >> 2, n0 = nt * 64;
    const int lane = t & 63, wid = t >> 6;
    const int wm = (wid & 1) * 16, wn = (wid >> 1) * 32;
    const int lr = lane & 15, lq = lane >> 4;
    const int r = t >> 3, c8 = (t & 7) * 8;

    const int nA = n0 + r, nB = n0 + r + 32;
    int kr0 = (nA < 128) ? (b * 100 + nA) : (800 + b * 100 + (nA - 128));
    int kr1 = (nB < 128) ? (b * 100 + nB) : (800 + b * 100 + (nB - 128));
    kr0 = kr0 > 1599 ? 1599 : kr0;
    kr1 = kr1 > 1599 ? 1599 : kr1;

    s16x8 ra, rb0, rb1;
#define LDSC(kt)                                                        \
    ra  = *(const s16x8*)(qh + (size_t)(m0 + r) * 512 + (kt) + c8);     \
    rb0 = cvt8(keys + (size_t)kr0 * 512 + (kt) + c8);                   \
    rb1 = cvt8(keys + (size_t)kr1 * 512 + (kt) + c8);

    f32x4 acc[2] = {};
    LDSC(0);
    for (int it = 0; it < 8; it++) {
        __syncthreads();
        *(s16x8*)&As[r * 72 + c8]        = ra;
        *(s16x8*)&Bs[r * 72 + c8]        = rb0;
        *(s16x8*)&Bs[(r + 32) * 72 + c8] = rb1;
        __syncthreads();
        if (it < 7) { LDSC((it + 1) * 64); }
#pragma unroll
        for (int s = 0; s < 2; s++) {
            s16x8 a0 = *(const s16x8*)&As[(wm + lr) * 72      + s * 32 + lq * 8];
            s16x8 b0 = *(const s16x8*)&Bs[(wn + lr) * 72      + s * 32 + lq * 8];
            s16x8 b1 = *(const s16x8*)&Bs[(wn + 16 + lr) * 72 + s * 32 + lq * 8];
            acc[0] = __builtin_amdgcn_mfma_f32_16x16x32_bf16(a0, b0, acc[0], 0, 0, 0);
            acc[1] = __builtin_amdgcn_mfma_f32_16x16x32_bf16(a0, b1, acc[1], 0, 0, 0);
        }
    }
#undef LDSC
#pragma unroll
    for (int j = 0; j < 2; j++) {
        const int col = n0 + wn + j * 16 + lr;
        const int row = m0 + wm + lq * 4;
        const float scale = (col >= 128) ? -(1.0f / 32.0f) : (1.0f / 32.0f);
#pragma unroll
        for (int rr = 0; rr < 4; rr++)
            sc[(size_t)(row + rr) * 256 + col] = acc[j][rr] * scale;
    }
}

// ---------------- stageD: softmax + wP GEMM -> atomic into out --------------
// grid (16 n-tiles, 8 b, 4 l-tiles) = 512 blocks of 32(l) x 32(n), K=200.
__global__ __launch_bounds__(256) void k_stageD(
    const float* __restrict__ sc, const float* __restrict__ P,
    float* __restrict__ out) {
    __shared__ float wbuf[200 * 33];     // [st][l], pad 33
    __shared__ float Bs[40 * 32];        // [k][n]

    const int t = threadIdx.x;
    const int b = blockIdx.y;
    const int n0 = blockIdx.x * 32;
    const int l0 = blockIdx.z * 32;
    const int wave = t >> 6, lane = t & 63;

    // ---- softmax: each wave handles 8 rows; lane covers cols lane*4..+3 ----
    for (int i = 0; i < 8; i++) {
        const int li = wave * 8 + i;                  // 0..31
        const float4 v = *(const float4*)(
            sc + (size_t)(b * 128 + l0 + li) * 256 + lane * 4);
        const float vv[4] = {v.x, v.y, v.z, v.w};
        const int c0 = lane * 4;
        float mS = -1e30f, mT = -1e30f;
#pragma unroll
        for (int j = 0; j < 4; j++) {
            const int col = c0 + j;
            if (col < 100) mS = fmaxf(mS, vv[j]);
            if (col >= 128 && col < 228) mT = fmaxf(mT, vv[j]);
        }
#pragma unroll
        for (int off = 32; off > 0; off >>= 1) {
            mS = fmaxf(mS, __shfl_xor(mS, off));
            mT = fmaxf(mT, __shfl_xor(mT, off));
        }
        float eS[4], eT[4], sS = 0.f, sT = 0.f;
#pragma unroll
        for (int j = 0; j < 4; j++) {
            const int col = c0 + j;
            eS[j] = (col < 100) ? __expf(vv[j] - mS) : 0.f;
            eT[j] = (col >= 128 && col < 228) ? __expf(vv[j] - mT) : 0.f;
            sS += eS[j]; sT += eT[j];
        }
#pragma unroll
        for (int off = 32; off > 0; off >>= 1) {
            sS += __shfl_xor(sS, off);
            sT += __shfl_xor(sT, off);
        }
        const float iS = 1.f / sS, iT = 1.f / sT;
#pragma unroll
        for (int j = 0; j < 4; j++) {
            const int col = c0 + j;
            if (col < 100) wbuf[col * 33 + li] = eS[j] * iS;
            if (col >= 128 && col < 228)
                wbuf[(100 + col - 128) * 33 + li] = eT[j] * iT;
        }
    }
    __syncthreads();

    // ---- GEMM: acc[l][n] += w[st][l] * (+P_s|-P_t)[st][n] ------------------
    const int tx = t & 7, ty = t >> 3;   // tx: n/4, ty: l
    float rB[5];
    auto loadB = [&](int kbase) {
#pragma unroll
        for (int e = 0; e < 5; e++) {
            const int idx = t + e * 256;
            const int k = idx >> 5, j = idx & 31;
            const int kk = kbase + k;
            rB[e] = (kk < 100)
                ?  P[(size_t)(b * 100 + kk) * 512 + n0 + j]
                : -P[(size_t)(800 + b * 100 + (kk - 100)) * 512 + n0 + j];
        }
    };

    float acc[4] = {};
    loadB(0);
    for (int c5 = 0; c5 < 5; c5++) {
        __syncthreads();
#pragma unroll
        for (int e = 0; e < 5; e++) {
            const int idx = t + e * 256;
            Bs[idx] = rB[e];
        }
        __syncthreads();
        if (c5 < 4) loadB((c5 + 1) * 40);          // prefetch next chunk
#pragma unroll 8
        for (int k = 0; k < 40; k++) {
            const float ar = wbuf[(c5 * 40 + k) * 33 + ty];
            float br[4];
            *(float4*)br = *(const float4*)&Bs[k * 32 + tx * 4];
#pragma unroll
            for (int j = 0; j < 4; j++) acc[j] = fmaf(ar, br[j], acc[j]);
        }
    }

    const float s2 = 0.70710678118654752f;  // 1/sqrt(2)
    const int m = b * 128 + l0 + ty;
#pragma unroll
    for (int j = 0; j < 4; j++)
        unsafeAtomicAdd(&out[(size_t)m * 512 + n0 + tx * 4 + j], acc[j] * s2);
}

// ---------------- launch ----------------------------------------------------

extern "C" void kernel_launch(void* const* d_in, const int* in_sizes, int n_in,
                              void* d_out, int out_size, void* d_ws, size_t ws_size,
                              hipStream_t stream) {
    const float* query = (const float*)d_in[0];
    const float* src   = (const float*)d_in[1];
    const float* trg   = (const float*)d_in[2];
    const float* Wq    = (const float*)d_in[3];
    const float* bq    = (const float*)d_in[4];
    const float* Ws    = (const float*)d_in[5];
    const float* Wo    = (const float*)d_in[7];
    const float* bo    = (const float*)d_in[8];
    float* out = (float*)d_out;

    // workspace layout (16B-aligned chunks)
    float* keys = (float*)d_ws;                          // 1600x512 fp32
    float* sc   = keys + 819200;                         // 1024x256 fp32
    float* P    = sc + 262144;                           // 1600x512 fp32
    unsigned short* qh  = (unsigned short*)(P + 819200); // 1024x512 bf16
    unsigned short* wqt = qh + 524288;                   // WqT 512x512 bf16
    unsigned short* wst = wqt + 262144;                  // WsT 512x2048 bf16
    unsigned short* wot = wst + 1048576;                 // WoT 512x1024 bf16

    k_prep<<<2080, 256, 0, stream>>>(Wq, Ws, wqt, wst, keys);
    k_stageB<<<1568, 256, 0, stream>>>(query, src, trg, wqt, wst, Wo, bq,
                                       qh, keys, wot);
    k_stageC<<<584, 256, 0, stream>>>(query, qh, keys, wot, bo, sc, P, out);
    k_stageD<<<dim3(16, 8, 4), 256, 0, stream>>>(sc, P, out);
}

// Round 12
// 135.674 us; speedup vs baseline: 1.1307x; 1.0072x over previous
//
#include <hip/hip_runtime.h>
#include <math.h>

// DynamicAttention1 — round 21: attack the TAIL (stageC+stageD ~= 85us).
// Cross-round algebra (R16/R17/R18-with-stage1=55/R20): stageB variants swung
// 22..55us while totals stayed ~134-137 -> stageB NOT critical path; prep~10,
// boundaries~5 -> stageC+stageD ~= 85us at 1.3-2/CU occupancy. Fixes:
//   1. stageD softmax: DROP max-subtraction (|score|<~8 -> exp safe in fp32);
//      single 5-step shfl_xor half-reduction (S in lanes 0-31, T in 32-63)
//      replaces 4x 6-step trees: 24 shfl + 8 exp -> 5 shfl + 4 exp per iter.
//   2. stageC: scgemm splitKx2 (256 blk x 4it, atomic onto zeroed sc; scale
//      commutes with the sum) + Pgemm m-split 32x64 (400 blk x 8it, direct) +
//      out_left 256 = 912 blocks (~3.6/CU), heavy jobs dispatched first.
//   3. prep: + sc-zero 256 blocks (2336 total). stageB unchanged from R20.
//   prep 2336 -> stageB 1568 (keys splitKx4 + qh + WoT) -> stageC 912 ->
//   stageD 512.
// keys UNBIASED everywhere (bs cancels in score diff and in ctx).

typedef __attribute__((ext_vector_type(8))) short s16x8;
typedef __attribute__((ext_vector_type(4))) float f32x4;

__device__ __forceinline__ unsigned short f2bf(float f) {
    unsigned int u = __float_as_uint(f);
    return (unsigned short)((u + 0x7fffu + ((u >> 16) & 1u)) >> 16);  // RNE
}

__device__ __forceinline__ s16x8 cvt8(const float* p) {
    float4 u = *(const float4*)p, w = *(const float4*)(p + 4);
    s16x8 o;
    o[0] = (short)f2bf(u.x); o[1] = (short)f2bf(u.y);
    o[2] = (short)f2bf(u.z); o[3] = (short)f2bf(u.w);
    o[4] = (short)f2bf(w.x); o[5] = (short)f2bf(w.y);
    o[6] = (short)f2bf(w.z); o[7] = (short)f2bf(w.w);
    return o;
}

// ---------------- prep: WqT/WsT transposes + keys zero + sc zero ------------
__global__ __launch_bounds__(256) void k_prep(
    const float* __restrict__ Wq, const float* __restrict__ Ws,
    unsigned short* __restrict__ WqT, unsigned short* __restrict__ WsT,
    float* __restrict__ keys, float* __restrict__ sc) {
    __shared__ float tile[32][33];
    const int id = blockIdx.x, t = threadIdx.x;

    if (id < 1280) {                        // weight transpose-cast, 32x32 tiles
        const float* W; unsigned short* O; int K, tk, tn;
        if (id < 256) { W = Wq; O = WqT; K = 512;  tk = id >> 4;         tn = id & 15; }
        else          { W = Ws; O = WsT; K = 2048; tk = (id - 256) >> 4; tn = (id - 256) & 15; }
        const int row = t >> 3, c4 = (t & 7) * 4;
        float4 v = *(const float4*)(W + (size_t)(tk * 32 + row) * 512 + tn * 32 + c4);
        tile[row][c4 + 0] = v.x; tile[row][c4 + 1] = v.y;
        tile[row][c4 + 2] = v.z; tile[row][c4 + 3] = v.w;
        __syncthreads();
        ushort4 o = make_ushort4(f2bf(tile[c4 + 0][row]), f2bf(tile[c4 + 1][row]),
                                 f2bf(tile[c4 + 2][row]), f2bf(tile[c4 + 3][row]));
        *(ushort4*)(O + (size_t)(tn * 32 + row) * K + tk * 32 + c4) = o;
    } else if (id < 2080) {                 // keys = 0 (split-K base)
        const int f = ((id - 1280) * 256 + t) * 4;
        *(float4*)(keys + f) = make_float4(0.f, 0.f, 0.f, 0.f);
    } else {                                // sc = 0 (scgemm split-K base)
        const int f = ((id - 2080) * 256 + t) * 4;
        *(float4*)(sc + f) = make_float4(0.f, 0.f, 0.f, 0.f);
    }
}

// ---------------- keys GEMM: splitKx4, A raw fp32, BT=wst bf16 --------------
// 64x64 tile, 4 waves 2x2; K-chunk 512 (8 iters), fp32 atomic epilogue.
__device__ __forceinline__ void gemm64_keys(
    const float* __restrict__ src, const float* __restrict__ trg,
    const unsigned short* __restrict__ BT, float* __restrict__ Kf,
    int m0, int n0, int kbase, unsigned short* As, unsigned short* Bs) {
    const int t = threadIdx.x;
    const int lane = t & 63, wid = t >> 6;
    const int wm = (wid & 1) * 32, wn = (wid >> 1) * 32;
    const int lr = lane & 15, lq = lane >> 4;
    const int r = t >> 3, c8 = (t & 7) * 8;

    const int ra_row = m0 + r, rb_row = m0 + r + 32;
    const float* arp = (ra_row < 800) ? (src + (size_t)ra_row * 2048)
                                      : (trg + (size_t)(ra_row - 800) * 2048);
    const float* brp = (rb_row < 800) ? (src + (size_t)rb_row * 2048)
                                      : (trg + (size_t)(rb_row - 800) * 2048);

    s16x8 ra0, ra1, rb0, rb1;
#define LDK(kt)                                                            \
    ra0 = cvt8(arp + (kt) + c8);                                           \
    ra1 = cvt8(brp + (kt) + c8);                                           \
    rb0 = *(const s16x8*)(BT + (size_t)(n0 + r)      * 2048 + (kt) + c8);  \
    rb1 = *(const s16x8*)(BT + (size_t)(n0 + r + 32) * 2048 + (kt) + c8);

    f32x4 acc[2][2] = {};
    LDK(kbase);
    for (int it = 0; it < 8; it++) {
        __syncthreads();
        *(s16x8*)&As[r * 72 + c8]        = ra0;
        *(s16x8*)&As[(r + 32) * 72 + c8] = ra1;
        *(s16x8*)&Bs[r * 72 + c8]        = rb0;
        *(s16x8*)&Bs[(r + 32) * 72 + c8] = rb1;
        __syncthreads();
        if (it < 7) { LDK(kbase + (it + 1) * 64); }  // prefetch
#pragma unroll
        for (int s = 0; s < 2; s++) {
            s16x8 a0 = *(const s16x8*)&As[(wm + lr) * 72      + s * 32 + lq * 8];
            s16x8 a1 = *(const s16x8*)&As[(wm + 16 + lr) * 72 + s * 32 + lq * 8];
            s16x8 b0 = *(const s16x8*)&Bs[(wn + lr) * 72      + s * 32 + lq * 8];
            s16x8 b1 = *(const s16x8*)&Bs[(wn + 16 + lr) * 72 + s * 32 + lq * 8];
            acc[0][0] = __builtin_amdgcn_mfma_f32_16x16x32_bf16(a0, b0, acc[0][0], 0, 0, 0);
            acc[0][1] = __builtin_amdgcn_mfma_f32_16x16x32_bf16(a0, b1, acc[0][1], 0, 0, 0);
            acc[1][0] = __builtin_amdgcn_mfma_f32_16x16x32_bf16(a1, b0, acc[1][0], 0, 0, 0);
            acc[1][1] = __builtin_amdgcn_mfma_f32_16x16x32_bf16(a1, b1, acc[1][1], 0, 0, 0);
        }
    }
#undef LDK
#pragma unroll
    for (int i = 0; i < 2; i++)
#pragma unroll
        for (int j = 0; j < 2; j++) {
            const int col = n0 + wn + j * 16 + lr;      // C/D: col=lane&15
            const int row = m0 + wm + i * 16 + lq * 4;  //      row=quad*4+reg
#pragma unroll
            for (int rr = 0; rr < 4; rr++)
                unsafeAtomicAdd(&Kf[(size_t)(row + rr) * 512 + col],
                                acc[i][j][rr]);
        }
}

// 32x64 tile, 4 waves. A fp32 (cvt in staging), BT bf16.
// MODE 0: fp32+bias store; 2: bf16+bias store; 4: fp32 no-bias store.
template <int MODE>
__device__ __forceinline__ void gemm32(
    const float* __restrict__ A, const unsigned short* __restrict__ BT,
    const float* __restrict__ bias, void* __restrict__ Cv,
    int m0, int n0, int KA, int KB, int N, int kiters,
    unsigned short* As, unsigned short* Bs) {
    const int t = threadIdx.x;
    const int lane = t & 63, wid = t >> 6;
    const int wm = (wid & 1) * 16, wn = (wid >> 1) * 32;
    const int lr = lane & 15, lq = lane >> 4;
    const int r = t >> 3, c8 = (t & 7) * 8;

    s16x8 ra, rb0, rb1;
#define LD32(kt)                                                            \
    ra  = cvt8(A + (size_t)(m0 + r) * KA + (kt) + c8);                      \
    rb0 = *(const s16x8*)(BT + (size_t)(n0 + r)      * KB + (kt) + c8);     \
    rb1 = *(const s16x8*)(BT + (size_t)(n0 + r + 32) * KB + (kt) + c8);

    f32x4 acc[2] = {};
    LD32(0);
    for (int it = 0; it < kiters; it++) {
        __syncthreads();
        *(s16x8*)&As[r * 72 + c8]        = ra;
        *(s16x8*)&Bs[r * 72 + c8]        = rb0;
        *(s16x8*)&Bs[(r + 32) * 72 + c8] = rb1;
        __syncthreads();
        if (it + 1 < kiters) { LD32((it + 1) * 64); }  // prefetch
#pragma unroll
        for (int s = 0; s < 2; s++) {
            s16x8 a0 = *(const s16x8*)&As[(wm + lr) * 72      + s * 32 + lq * 8];
            s16x8 b0 = *(const s16x8*)&Bs[(wn + lr) * 72      + s * 32 + lq * 8];
            s16x8 b1 = *(const s16x8*)&Bs[(wn + 16 + lr) * 72 + s * 32 + lq * 8];
            acc[0] = __builtin_amdgcn_mfma_f32_16x16x32_bf16(a0, b0, acc[0], 0, 0, 0);
            acc[1] = __builtin_amdgcn_mfma_f32_16x16x32_bf16(a0, b1, acc[1], 0, 0, 0);
        }
    }
#undef LD32
#pragma unroll
    for (int j = 0; j < 2; j++) {
        const int col = n0 + wn + j * 16 + lr;
        const int row = m0 + wm + lq * 4;
        if (MODE == 0) {
            const float bv = bias[col];
            float* C = (float*)Cv;
#pragma unroll
            for (int rr = 0; rr < 4; rr++)
                C[(size_t)(row + rr) * N + col] = acc[j][rr] + bv;
        } else if (MODE == 2) {
            const float bv = bias[col];
            unsigned short* C = (unsigned short*)Cv;
#pragma unroll
            for (int rr = 0; rr < 4; rr++)
                C[(size_t)(row + rr) * N + col] = f2bf(acc[j][rr] + bv);
        } else {
            float* C = (float*)Cv;
#pragma unroll
            for (int rr = 0; rr < 4; rr++)
                C[(size_t)(row + rr) * N + col] = acc[j][rr];
        }
    }
}

// ---------------- stageB: keys 800 (splitKx4) + qh 256 + WoT 512 ------------
__global__ __launch_bounds__(256) void k_stageB(
    const float* __restrict__ query, const float* __restrict__ src,
    const float* __restrict__ trg, const unsigned short* __restrict__ wqt,
    const unsigned short* __restrict__ wst, const float* __restrict__ Wo,
    const float* __restrict__ bq, unsigned short* __restrict__ qh,
    float* __restrict__ keys, unsigned short* __restrict__ wot) {
    __shared__ __align__(16) unsigned short As[64 * 72];
    __shared__ __align__(16) unsigned short Bs[64 * 72];
    const int bid = blockIdx.x, t = threadIdx.x;

    if (bid < 800) {
        const int c = bid / 200, rem = bid % 200;
        gemm64_keys(src, trg, wst, keys, (rem >> 3) * 64, (rem & 7) * 64,
                    c * 512, As, Bs);
    } else if (bid < 1056) {
        const int rr = bid - 800;
        gemm32<2>(query, wqt, bq, qh, (rr >> 3) * 32, (rr & 7) * 64,
                  512, 512, 512, 8, As, Bs);
    } else {
        // WoT transpose: Wo[1024][512] -> wot[n=512][k=1024], 32x32 tiles
        float (*tile)[33] = (float(*)[33])As;   // 4.2KB alias over As
        const int id2 = bid - 1056;             // 0..511
        const int tk = id2 >> 4, tn = id2 & 15;
        const int row = t >> 3, c4 = (t & 7) * 4;
        float4 v = *(const float4*)(Wo + (size_t)(tk * 32 + row) * 512 + tn * 32 + c4);
        tile[row][c4 + 0] = v.x; tile[row][c4 + 1] = v.y;
        tile[row][c4 + 2] = v.z; tile[row][c4 + 3] = v.w;
        __syncthreads();
        ushort4 o = make_ushort4(f2bf(tile[c4 + 0][row]), f2bf(tile[c4 + 1][row]),
                                 f2bf(tile[c4 + 2][row]), f2bf(tile[c4 + 3][row]));
        *(ushort4*)(wot + (size_t)(tn * 32 + row) * 1024 + tk * 32 + c4) = o;
    }
}

// ---------------- stageC: Pgemm 400 + out_left 256 + scgemm splitKx2 256 ----
__global__ __launch_bounds__(256) void k_stageC(
    const float* __restrict__ query, const unsigned short* __restrict__ qh,
    const float* __restrict__ keys, const unsigned short* __restrict__ wot,
    const float* __restrict__ bo, float* __restrict__ sc,
    float* __restrict__ P, float* __restrict__ out) {
    __shared__ __align__(16) unsigned short As[64 * 72];
    __shared__ __align__(16) unsigned short Bs[64 * 72];
    const int bid = blockIdx.x;
    const int t = threadIdx.x;

    if (bid < 400) {                        // ---- Pgemm (32x64 tiles) ----
        gemm32<4>(keys, wot + 512, nullptr, P, (bid >> 3) * 32,
                  (bid & 7) * 64, 512, 1024, 512, 8, As, Bs);
        return;
    }
    if (bid < 656) {                        // ---- out_left ----
        const int rr = bid - 400;
        gemm32<0>(query, wot, bo, out, (rr >> 3) * 32, (rr & 7) * 64,
                  512, 1024, 512, 8, As, Bs);
        return;
    }

    // ---- scgemm splitKx2: 256 blocks x 4 iters, atomic onto zeroed sc ----
    const int sid = bid - 656;              // 0..255
    const int half = sid >> 7, rem = sid & 127;
    const int kbase = half * 256;
    const int mt = rem >> 2, nt = rem & 3;
    const int m0 = mt * 32, b = mt >> 2, n0 = nt * 64;
    const int lane = t & 63, wid = t >> 6;
    const int wm = (wid & 1) * 16, wn = (wid >> 1) * 32;
    const int lr = lane & 15, lq = lane >> 4;
    const int r = t >> 3, c8 = (t & 7) * 8;

    const int nA = n0 + r, nB = n0 + r + 32;
    int kr0 = (nA < 128) ? (b * 100 + nA) : (800 + b * 100 + (nA - 128));
    int kr1 = (nB < 128) ? (b * 100 + nB) : (800 + b * 100 + (nB - 128));
    kr0 = kr0 > 1599 ? 1599 : kr0;
    kr1 = kr1 > 1599 ? 1599 : kr1;

    s16x8 ra, rb0, rb1;
#define LDSC(kt)                                                        \
    ra  = *(const s16x8*)(qh + (size_t)(m0 + r) * 512 + (kt) + c8);     \
    rb0 = cvt8(keys + (size_t)kr0 * 512 + (kt) + c8);                   \
    rb1 = cvt8(keys + (size_t)kr1 * 512 + (kt) + c8);

    f32x4 acc[2] = {};
    LDSC(kbase);
    for (int it = 0; it < 4; it++) {
        __syncthreads();
        *(s16x8*)&As[r * 72 + c8]        = ra;
        *(s16x8*)&Bs[r * 72 + c8]        = rb0;
        *(s16x8*)&Bs[(r + 32) * 72 + c8] = rb1;
        __syncthreads();
        if (it < 3) { LDSC(kbase + (it + 1) * 64); }
#pragma unroll
        for (int s = 0; s < 2; s++) {
            s16x8 a0 = *(const s16x8*)&As[(wm + lr) * 72      + s * 32 + lq * 8];
            s16x8 b0 = *(const s16x8*)&Bs[(wn + lr) * 72      + s * 32 + lq * 8];
            s16x8 b1 = *(const s16x8*)&Bs[(wn + 16 + lr) * 72 + s * 32 + lq * 8];
            acc[0] = __builtin_amdgcn_mfma_f32_16x16x32_bf16(a0, b0, acc[0], 0, 0, 0);
            acc[1] = __builtin_amdgcn_mfma_f32_16x16x32_bf16(a0, b1, acc[1], 0, 0, 0);
        }
    }
#undef LDSC
#pragma unroll
    for (int j = 0; j < 2; j++) {
        const int col = n0 + wn + j * 16 + lr;
        const int row = m0 + wm + lq * 4;
        const float scale = (col >= 128) ? -(1.0f / 32.0f) : (1.0f / 32.0f);
#pragma unroll
        for (int rr = 0; rr < 4; rr++)
            unsafeAtomicAdd(&sc[(size_t)(row + rr) * 256 + col],
                            acc[j][rr] * scale);
    }
}

// ---------------- stageD: cheap softmax + wP GEMM -> atomic into out --------
// grid (16 n-tiles, 8 b, 4 l-tiles) = 512 blocks of 32(l) x 32(n), K=200.
// Softmax WITHOUT max-subtraction: |score| < ~8 (scores ~N(0,0.7)), exp is
// safe in fp32. S-cols live in lanes 0..31, T-cols in lanes 32..63 -> one
// 5-step shfl_xor (offsets <=16) reduces each half independently.
__global__ __launch_bounds__(256) void k_stageD(
    const float* __restrict__ sc, const float* __restrict__ P,
    float* __restrict__ out) {
    __shared__ float wbuf[200 * 33];     // [st][l], pad 33
    __shared__ float Bs[40 * 32];        // [k][n]

    const int t = threadIdx.x;
    const int b = blockIdx.y;
    const int n0 = blockIdx.x * 32;
    const int l0 = blockIdx.z * 32;
    const int wave = t >> 6, lane = t & 63;

    // ---- softmax (no-max, half-reduce) ----
    for (int i = 0; i < 8; i++) {
        const int li = wave * 8 + i;                  // 0..31
        const float4 v = *(const float4*)(
            sc + (size_t)(b * 128 + l0 + li) * 256 + lane * 4);
        const float vv[4] = {v.x, v.y, v.z, v.w};
        const int c0 = lane * 4;
        float e[4], s = 0.f;
#pragma unroll
        for (int j = 0; j < 4; j++) {
            const int col = c0 + j;
            const bool valid = (col < 100) | (col >= 128 && col < 228);
            e[j] = valid ? __expf(vv[j]) : 0.f;
            s += e[j];
        }
#pragma unroll
        for (int off = 16; off > 0; off >>= 1) s += __shfl_xor(s, off);
        const float inv = 1.f / s;                    // lanes<32: 1/sS; >=32: 1/sT
#pragma unroll
        for (int j = 0; j < 4; j++) {
            const int col = c0 + j;
            if (col < 100) wbuf[col * 33 + li] = e[j] * inv;
            else if (col >= 128 && col < 228)
                wbuf[(100 + col - 128) * 33 + li] = e[j] * inv;
        }
    }
    __syncthreads();

    // ---- GEMM: acc[l][n] += w[st][l] * (+P_s|-P_t)[st][n] ------------------
    const int tx = t & 7, ty = t >> 3;   // tx: n/4, ty: l
    float rB[5];
    auto loadB = [&](int kbase) {
#pragma unroll
        for (int e2 = 0; e2 < 5; e2++) {
            const int idx = t + e2 * 256;
            const int k = idx >> 5, j = idx & 31;
            const int kk = kbase + k;
            rB[e2] = (kk < 100)
                ?  P[(size_t)(b * 100 + kk) * 512 + n0 + j]
                : -P[(size_t)(800 + b * 100 + (kk - 100)) * 512 + n0 + j];
        }
    };

    float acc[4] = {};
    loadB(0);
    for (int c5 = 0; c5 < 5; c5++) {
        __syncthreads();
#pragma unroll
        for (int e2 = 0; e2 < 5; e2++) {
            const int idx = t + e2 * 256;
            Bs[idx] = rB[e2];
        }
        __syncthreads();
        if (c5 < 4) loadB((c5 + 1) * 40);          // prefetch next chunk
#pragma unroll 8
        for (int k = 0; k < 40; k++) {
            const float ar = wbuf[(c5 * 40 + k) * 33 + ty];
            float br[4];
            *(float4*)br = *(const float4*)&Bs[k * 32 + tx * 4];
#pragma unroll
            for (int j = 0; j < 4; j++) acc[j] = fmaf(ar, br[j], acc[j]);
        }
    }

    const float s2 = 0.70710678118654752f;  // 1/sqrt(2)
    const int m = b * 128 + l0 + ty;
#pragma unroll
    for (int j = 0; j < 4; j++)
        unsafeAtomicAdd(&out[(size_t)m * 512 + n0 + tx * 4 + j], acc[j] * s2);
}

// ---------------- launch ----------------------------------------------------

extern "C" void kernel_launch(void* const* d_in, const int* in_sizes, int n_in,
                              void* d_out, int out_size, void* d_ws, size_t ws_size,
                              hipStream_t stream) {
    const float* query = (const float*)d_in[0];
    const float* src   = (const float*)d_in[1];
    const float* trg   = (const float*)d_in[2];
    const float* Wq    = (const float*)d_in[3];
    const float* bq    = (const float*)d_in[4];
    const float* Ws    = (const float*)d_in[5];
    const float* Wo    = (const float*)d_in[7];
    const float* bo    = (const float*)d_in[8];
    float* out = (float*)d_out;

    // workspace layout (16B-aligned chunks)
    float* keys = (float*)d_ws;                          // 1600x512 fp32
    float* sc   = keys + 819200;                         // 1024x256 fp32
    float* P    = sc + 262144;                           // 1600x512 fp32
    unsigned short* qh  = (unsigned short*)(P + 819200); // 1024x512 bf16
    unsigned short* wqt = qh + 524288;                   // WqT 512x512 bf16
    unsigned short* wst = wqt + 262144;                  // WsT 512x2048 bf16
    unsigned short* wot = wst + 1048576;                 // WoT 512x1024 bf16

    k_prep<<<2336, 256, 0, stream>>>(Wq, Ws, wqt, wst, keys, sc);
    k_stageB<<<1568, 256, 0, stream>>>(query, src, trg, wqt, wst, Wo, bq,
                                       qh, keys, wot);
    k_stageC<<<912, 256, 0, stream>>>(query, qh, keys, wot, bo, sc, P, out);
    k_stageD<<<dim3(16, 8, 4), 256, 0, stream>>>(sc, P, out);
}

// Round 13
// 130.666 us; speedup vs baseline: 1.1740x; 1.0383x over previous
//
#include <hip/hip_runtime.h>
#include <math.h>

// DynamicAttention1 — round 22: RE-ANCHOR — byte-identical resubmit of the
// session-start R12 kernel (the only config ever measured at 129.6us).
// R21 post-mortem: every stage-internal fix (softmax 5x cheaper, stageC
// occupancy 1.3->3.6/CU, splitK variants, traffic cuts) is NULL on total;
// all 4-launch variants land 133-137 while R12 measured 129.6. This round
// decides: (a) ~129-131 -> R12's structure (splitKx2/16it, out_left in
// stageB, WoT in prep) carries a real ~6us edge -> isolate axis next round;
// (b) ~134-136 -> harness floor drifted, all variants equivalent, pipeline
// is launch-structure-bound.

typedef __attribute__((ext_vector_type(8))) short s16x8;
typedef __attribute__((ext_vector_type(4))) float f32x4;

__device__ __forceinline__ unsigned short f2bf(float f) {
    unsigned int u = __float_as_uint(f);
    return (unsigned short)((u + 0x7fffu + ((u >> 16) & 1u)) >> 16);  // RNE
}

__device__ __forceinline__ s16x8 cvt8(const float* p) {
    float4 u = *(const float4*)p, w = *(const float4*)(p + 4);
    s16x8 o;
    o[0] = (short)f2bf(u.x); o[1] = (short)f2bf(u.y);
    o[2] = (short)f2bf(u.z); o[3] = (short)f2bf(u.w);
    o[4] = (short)f2bf(w.x); o[5] = (short)f2bf(w.y);
    o[6] = (short)f2bf(w.z); o[7] = (short)f2bf(w.w);
    return o;
}

// ---------------- prep: weight transposes + keys zero-init ------------------
__global__ __launch_bounds__(256) void k_prep(
    const float* __restrict__ Wq, const float* __restrict__ Ws,
    const float* __restrict__ Wo,
    unsigned short* __restrict__ WqT, unsigned short* __restrict__ WsT,
    unsigned short* __restrict__ WoT, float* __restrict__ keys) {
    __shared__ float tile[32][33];
    const int bid = blockIdx.x, t = threadIdx.x;

    if (bid < 1792) {                       // weight transpose-cast, 32x32 tiles
        const int id = bid;
        const float* W; unsigned short* O; int K, tk, tn;
        if (id < 256)       { W = Wq; O = WqT; K = 512;  tk = id >> 4;          tn = id & 15; }
        else if (id < 1280) { W = Ws; O = WsT; K = 2048; tk = (id - 256) >> 4;  tn = (id - 256) & 15; }
        else                { W = Wo; O = WoT; K = 1024; tk = (id - 1280) >> 4; tn = (id - 1280) & 15; }
        const int row = t >> 3, c4 = (t & 7) * 4;
        float4 v = *(const float4*)(W + (size_t)(tk * 32 + row) * 512 + tn * 32 + c4);
        tile[row][c4 + 0] = v.x; tile[row][c4 + 1] = v.y;
        tile[row][c4 + 2] = v.z; tile[row][c4 + 3] = v.w;
        __syncthreads();
        ushort4 o = make_ushort4(f2bf(tile[c4 + 0][row]), f2bf(tile[c4 + 1][row]),
                                 f2bf(tile[c4 + 2][row]), f2bf(tile[c4 + 3][row]));
        *(ushort4*)(O + (size_t)(tn * 32 + row) * K + tk * 32 + c4) = o;
    } else {                                // keys = 0 (split-K base, unbiased)
        const int f = ((bid - 1792) * 256 + t) * 4;
        *(float4*)(keys + f) = make_float4(0.f, 0.f, 0.f, 0.f);
    }
}

// ---------------- keys GEMM: A = [src;trg] fp32 (cvt in staging) ------------
// 64x64 tile, 4 waves 2x2; split-K x2, atomics onto zeroed keys.
__device__ __forceinline__ void gemm64_keys(
    const float* __restrict__ src, const float* __restrict__ trg,
    const unsigned short* __restrict__ BT, float* __restrict__ C,
    int m0, int n0, int kbase, unsigned short* As, unsigned short* Bs) {
    const int t = threadIdx.x;
    const int lane = t & 63, wid = t >> 6;
    const int wm = (wid & 1) * 32, wn = (wid >> 1) * 32;
    const int lr = lane & 15, lq = lane >> 4;
    const int r = t >> 3, c8 = (t & 7) * 8;

    const int ra_row = m0 + r, rb_row = m0 + r + 32;
    const float* arp = (ra_row < 800) ? (src + (size_t)ra_row * 2048)
                                      : (trg + (size_t)(ra_row - 800) * 2048);
    const float* brp = (rb_row < 800) ? (src + (size_t)rb_row * 2048)
                                      : (trg + (size_t)(rb_row - 800) * 2048);

    s16x8 ra0, ra1, rb0, rb1;
#define LDK(kt)                                                            \
    ra0 = cvt8(arp + (kt) + c8);                                           \
    ra1 = cvt8(brp + (kt) + c8);                                           \
    rb0 = *(const s16x8*)(BT + (size_t)(n0 + r)      * 2048 + (kt) + c8);  \
    rb1 = *(const s16x8*)(BT + (size_t)(n0 + r + 32) * 2048 + (kt) + c8);

    f32x4 acc[2][2] = {};
    LDK(kbase);
    for (int it = 0; it < 16; it++) {
        __syncthreads();
        *(s16x8*)&As[r * 72 + c8]        = ra0;
        *(s16x8*)&As[(r + 32) * 72 + c8] = ra1;
        *(s16x8*)&Bs[r * 72 + c8]        = rb0;
        *(s16x8*)&Bs[(r + 32) * 72 + c8] = rb1;
        __syncthreads();
        if (it < 15) { LDK(kbase + (it + 1) * 64); }  // prefetch
#pragma unroll
        for (int s = 0; s < 2; s++) {
            s16x8 a0 = *(const s16x8*)&As[(wm + lr) * 72      + s * 32 + lq * 8];
            s16x8 a1 = *(const s16x8*)&As[(wm + 16 + lr) * 72 + s * 32 + lq * 8];
            s16x8 b0 = *(const s16x8*)&Bs[(wn + lr) * 72      + s * 32 + lq * 8];
            s16x8 b1 = *(const s16x8*)&Bs[(wn + 16 + lr) * 72 + s * 32 + lq * 8];
            acc[0][0] = __builtin_amdgcn_mfma_f32_16x16x32_bf16(a0, b0, acc[0][0], 0, 0, 0);
            acc[0][1] = __builtin_amdgcn_mfma_f32_16x16x32_bf16(a0, b1, acc[0][1], 0, 0, 0);
            acc[1][0] = __builtin_amdgcn_mfma_f32_16x16x32_bf16(a1, b0, acc[1][0], 0, 0, 0);
            acc[1][1] = __builtin_amdgcn_mfma_f32_16x16x32_bf16(a1, b1, acc[1][1], 0, 0, 0);
        }
    }
#undef LDK
#pragma unroll
    for (int i = 0; i < 2; i++)
#pragma unroll
        for (int j = 0; j < 2; j++) {
            const int col = n0 + wn + j * 16 + lr;      // C/D: col=lane&15
            const int row = m0 + wm + i * 16 + lq * 4;  //      row=quad*4+reg
#pragma unroll
            for (int rr = 0; rr < 4; rr++)
                unsafeAtomicAdd(&C[(size_t)(row + rr) * 512 + col], acc[i][j][rr]);
        }
}

// ---------------- P GEMM: P = keys @ WoBot (direct fp32 store) --------------
// 64x64 tile, 4 waves 2x2, K=512 (8 iters). A = keys fp32 cvt, B = wot+512.
__device__ __forceinline__ void gemm64_P(
    const float* __restrict__ keys, const unsigned short* __restrict__ wotBot,
    float* __restrict__ P, int m0, int n0, unsigned short* As,
    unsigned short* Bs) {
    const int t = threadIdx.x;
    const int lane = t & 63, wid = t >> 6;
    const int wm = (wid & 1) * 32, wn = (wid >> 1) * 32;
    const int lr = lane & 15, lq = lane >> 4;
    const int r = t >> 3, c8 = (t & 7) * 8;

    s16x8 ra0, ra1, rb0, rb1;
#define LDP(kt)                                                               \
    ra0 = cvt8(keys + (size_t)(m0 + r)      * 512 + (kt) + c8);               \
    ra1 = cvt8(keys + (size_t)(m0 + r + 32) * 512 + (kt) + c8);               \
    rb0 = *(const s16x8*)(wotBot + (size_t)(n0 + r)      * 1024 + (kt) + c8); \
    rb1 = *(const s16x8*)(wotBot + (size_t)(n0 + r + 32) * 1024 + (kt) + c8);

    f32x4 acc[2][2] = {};
    LDP(0);
    for (int it = 0; it < 8; it++) {
        __syncthreads();
        *(s16x8*)&As[r * 72 + c8]        = ra0;
        *(s16x8*)&As[(r + 32) * 72 + c8] = ra1;
        *(s16x8*)&Bs[r * 72 + c8]        = rb0;
        *(s16x8*)&Bs[(r + 32) * 72 + c8] = rb1;
        __syncthreads();
        if (it < 7) { LDP((it + 1) * 64); }  // prefetch
#pragma unroll
        for (int s = 0; s < 2; s++) {
            s16x8 a0 = *(const s16x8*)&As[(wm + lr) * 72      + s * 32 + lq * 8];
            s16x8 a1 = *(const s16x8*)&As[(wm + 16 + lr) * 72 + s * 32 + lq * 8];
            s16x8 b0 = *(const s16x8*)&Bs[(wn + lr) * 72      + s * 32 + lq * 8];
            s16x8 b1 = *(const s16x8*)&Bs[(wn + 16 + lr) * 72 + s * 32 + lq * 8];
            acc[0][0] = __builtin_amdgcn_mfma_f32_16x16x32_bf16(a0, b0, acc[0][0], 0, 0, 0);
            acc[0][1] = __builtin_amdgcn_mfma_f32_16x16x32_bf16(a0, b1, acc[0][1], 0, 0, 0);
            acc[1][0] = __builtin_amdgcn_mfma_f32_16x16x32_bf16(a1, b0, acc[1][0], 0, 0, 0);
            acc[1][1] = __builtin_amdgcn_mfma_f32_16x16x32_bf16(a1, b1, acc[1][1], 0, 0, 0);
        }
    }
#undef LDP
#pragma unroll
    for (int i = 0; i < 2; i++)
#pragma unroll
        for (int j = 0; j < 2; j++) {
            const int col = n0 + wn + j * 16 + lr;
            const int row = m0 + wm + i * 16 + lq * 4;
#pragma unroll
            for (int rr = 0; rr < 4; rr++)
                P[(size_t)(row + rr) * 512 + col] = acc[i][j][rr];
        }
}

// 32x64 tile, 4 waves. A fp32 (cvt in staging). MODE 0: fp32+bias,
// 2: bf16+bias.
template <int MODE>
__device__ __forceinline__ void gemm32(
    const float* __restrict__ A, const unsigned short* __restrict__ BT,
    const float* __restrict__ bias, void* __restrict__ Cv,
    int m0, int n0, int KA, int KB, int N, int kiters,
    unsigned short* As, unsigned short* Bs) {
    const int t = threadIdx.x;
    const int lane = t & 63, wid = t >> 6;
    const int wm = (wid & 1) * 16, wn = (wid >> 1) * 32;
    const int lr = lane & 15, lq = lane >> 4;
    const int r = t >> 3, c8 = (t & 7) * 8;

    s16x8 ra, rb0, rb1;
#define LD32(kt)                                                            \
    ra  = cvt8(A + (size_t)(m0 + r) * KA + (kt) + c8);                      \
    rb0 = *(const s16x8*)(BT + (size_t)(n0 + r)      * KB + (kt) + c8);     \
    rb1 = *(const s16x8*)(BT + (size_t)(n0 + r + 32) * KB + (kt) + c8);

    f32x4 acc[2] = {};
    LD32(0);
    for (int it = 0; it < kiters; it++) {
        __syncthreads();
        *(s16x8*)&As[r * 72 + c8]        = ra;
        *(s16x8*)&Bs[r * 72 + c8]        = rb0;
        *(s16x8*)&Bs[(r + 32) * 72 + c8] = rb1;
        __syncthreads();
        if (it + 1 < kiters) { LD32((it + 1) * 64); }  // prefetch
#pragma unroll
        for (int s = 0; s < 2; s++) {
            s16x8 a0 = *(const s16x8*)&As[(wm + lr) * 72      + s * 32 + lq * 8];
            s16x8 b0 = *(const s16x8*)&Bs[(wn + lr) * 72      + s * 32 + lq * 8];
            s16x8 b1 = *(const s16x8*)&Bs[(wn + 16 + lr) * 72 + s * 32 + lq * 8];
            acc[0] = __builtin_amdgcn_mfma_f32_16x16x32_bf16(a0, b0, acc[0], 0, 0, 0);
            acc[1] = __builtin_amdgcn_mfma_f32_16x16x32_bf16(a0, b1, acc[1], 0, 0, 0);
        }
    }
#undef LD32
#pragma unroll
    for (int j = 0; j < 2; j++) {
        const int col = n0 + wn + j * 16 + lr;
        const int row = m0 + wm + lq * 4;
        const float bv = bias[col];
        if (MODE == 0) {
            float* C = (float*)Cv;
#pragma unroll
            for (int rr = 0; rr < 4; rr++)
                C[(size_t)(row + rr) * N + col] = acc[j][rr] + bv;
        } else {
            unsigned short* C = (unsigned short*)Cv;
#pragma unroll
            for (int rr = 0; rr < 4; rr++)
                C[(size_t)(row + rr) * N + col] = f2bf(acc[j][rr] + bv);
        }
    }
}

// ---------------- stage B: keys splitKx2 + qh + out_left --------------------
__global__ __launch_bounds__(256) void k_stageB(
    const float* __restrict__ query, const float* __restrict__ src,
    const float* __restrict__ trg, const unsigned short* __restrict__ WqT,
    const unsigned short* __restrict__ WsT, const unsigned short* __restrict__ WoT,
    const float* __restrict__ bq, const float* __restrict__ bo,
    unsigned short* __restrict__ qh, float* __restrict__ keys,
    float* __restrict__ out) {
    __shared__ __align__(16) unsigned short As[64 * 72];
    __shared__ __align__(16) unsigned short Bs[64 * 72];
    const int bid = blockIdx.x;
    if (bid < 400) {
        const int c = bid / 200, rem = bid % 200;
        const int mt = rem >> 3, nt = rem & 7;
        gemm64_keys(src, trg, WsT, keys, mt * 64, nt * 64, c * 1024, As, Bs);
    } else if (bid < 656) {
        const int r = bid - 400;
        const int mt = r >> 3, nt = r & 7;
        gemm32<2>(query, WqT, bq, qh, mt * 32, nt * 64, 512, 512, 512,
                  8, As, Bs);
    } else {
        const int r = bid - 656;
        const int mt = r >> 3, nt = r & 7;
        gemm32<0>(query, WoT, bo, out, mt * 32, nt * 64, 512, 1024, 512,
                  8, As, Bs);
    }
}

// ---------------- stage C: scgemm (128 blocks) + Pgemm (200 blocks) ---------
// scgemm: sc[b*128+l][n], cols 0..99 = qs/32, cols 128..227 = -qt/32.
// Pgemm:  P = keys @ WoBot, [1600][512] fp32 direct.
__global__ __launch_bounds__(256) void k_stageC(
    const unsigned short* __restrict__ qh, const float* __restrict__ keys,
    const unsigned short* __restrict__ wotBot, float* __restrict__ sc,
    float* __restrict__ P) {
    __shared__ __align__(16) unsigned short As[64 * 72];
    __shared__ __align__(16) unsigned short Bs[64 * 72];
    const int bid = blockIdx.x;
    const int t = threadIdx.x;

    if (bid >= 128) {                       // ---- Pgemm ----
        const int rem = bid - 128;
        gemm64_P(keys, wotBot, P, (rem >> 3) * 64, (rem & 7) * 64, As, Bs);
        return;
    }

    // ---- scgemm ----
    const int mt = bid >> 2, nt = bid & 3;
    const int m0 = mt * 32, b = mt >> 2, n0 = nt * 64;
    const int lane = t & 63, wid = t >> 6;
    const int wm = (wid & 1) * 16, wn = (wid >> 1) * 32;
    const int lr = lane & 15, lq = lane >> 4;
    const int r = t >> 3, c8 = (t & 7) * 8;

    const int nA = n0 + r, nB = n0 + r + 32;
    int kr0 = (nA < 128) ? (b * 100 + nA) : (800 + b * 100 + (nA - 128));
    int kr1 = (nB < 128) ? (b * 100 + nB) : (800 + b * 100 + (nB - 128));
    kr0 = kr0 > 1599 ? 1599 : kr0;
    kr1 = kr1 > 1599 ? 1599 : kr1;

    s16x8 ra, rb0, rb1;
#define LDSC(kt)                                                    \
    ra  = *(const s16x8*)(qh + (size_t)(m0 + r) * 512 + (kt) + c8); \
    rb0 = cvt8(keys + (size_t)kr0 * 512 + (kt) + c8);               \
    rb1 = cvt8(keys + (size_t)kr1 * 512 + (kt) + c8);

    f32x4 acc[2] = {};
    LDSC(0);
    for (int it = 0; it < 8; it++) {
        __syncthreads();
        *(s16x8*)&As[r * 72 + c8]        = ra;
        *(s16x8*)&Bs[r * 72 + c8]        = rb0;
        *(s16x8*)&Bs[(r + 32) * 72 + c8] = rb1;
        __syncthreads();
        if (it < 7) { LDSC((it + 1) * 64); }
#pragma unroll
        for (int s = 0; s < 2; s++) {
            s16x8 a0 = *(const s16x8*)&As[(wm + lr) * 72      + s * 32 + lq * 8];
            s16x8 b0 = *(const s16x8*)&Bs[(wn + lr) * 72      + s * 32 + lq * 8];
            s16x8 b1 = *(const s16x8*)&Bs[(wn + 16 + lr) * 72 + s * 32 + lq * 8];
            acc[0] = __builtin_amdgcn_mfma_f32_16x16x32_bf16(a0, b0, acc[0], 0, 0, 0);
            acc[1] = __builtin_amdgcn_mfma_f32_16x16x32_bf16(a0, b1, acc[1], 0, 0, 0);
        }
    }
#undef LDSC
#pragma unroll
    for (int j = 0; j < 2; j++) {
        const int col = n0 + wn + j * 16 + lr;
        const int row = m0 + wm + lq * 4;
        const float scale = (col >= 128) ? -(1.0f / 32.0f) : (1.0f / 32.0f);
#pragma unroll
        for (int rr = 0; rr < 4; rr++)
            sc[(size_t)(row + rr) * 256 + col] = acc[j][rr] * scale;
    }
}

// ---------------- stage D: softmax + wP GEMM -> atomic into out -------------
// grid (16 n-tiles, 8 b, 4 l-tiles) = 512 blocks of 32(l) x 32(n), K=200.
// out[m][n] += (sum_s ws*P_s - sum_t wt*P_t)/sqrt2  (out has out_left+bo).
__global__ __launch_bounds__(256) void k_stageD(
    const float* __restrict__ sc, const float* __restrict__ P,
    float* __restrict__ out) {
    __shared__ float wbuf[200 * 33];     // [st][l], pad 33
    __shared__ float Bs[40 * 32];        // [k][n]

    const int t = threadIdx.x;
    const int b = blockIdx.y;
    const int n0 = blockIdx.x * 32;
    const int l0 = blockIdx.z * 32;
    const int wave = t >> 6, lane = t & 63;

    // ---- softmax: each wave handles 8 rows; lane covers cols lane*4..+3 ----
    for (int i = 0; i < 8; i++) {
        const int li = wave * 8 + i;                  // 0..31
        const float4 v = *(const float4*)(
            sc + (size_t)(b * 128 + l0 + li) * 256 + lane * 4);
        const float vv[4] = {v.x, v.y, v.z, v.w};
        const int c0 = lane * 4;
        float mS = -1e30f, mT = -1e30f;
#pragma unroll
        for (int j = 0; j < 4; j++) {
            const int col = c0 + j;
            if (col < 100) mS = fmaxf(mS, vv[j]);
            if (col >= 128 && col < 228) mT = fmaxf(mT, vv[j]);
        }
#pragma unroll
        for (int off = 32; off > 0; off >>= 1) {
            mS = fmaxf(mS, __shfl_xor(mS, off));
            mT = fmaxf(mT, __shfl_xor(mT, off));
        }
        float eS[4], eT[4], sS = 0.f, sT = 0.f;
#pragma unroll
        for (int j = 0; j < 4; j++) {
            const int col = c0 + j;
            eS[j] = (col < 100) ? __expf(vv[j] - mS) : 0.f;
            eT[j] = (col >= 128 && col < 228) ? __expf(vv[j] - mT) : 0.f;
            sS += eS[j]; sT += eT[j];
        }
#pragma unroll
        for (int off = 32; off > 0; off >>= 1) {
            sS += __shfl_xor(sS, off);
            sT += __shfl_xor(sT, off);
        }
        const float iS = 1.f / sS, iT = 1.f / sT;
#pragma unroll
        for (int j = 0; j < 4; j++) {
            const int col = c0 + j;
            if (col < 100) wbuf[col * 33 + li] = eS[j] * iS;
            if (col >= 128 && col < 228)
                wbuf[(100 + col - 128) * 33 + li] = eT[j] * iT;
        }
    }
    __syncthreads();

    // ---- GEMM: acc[l][n] += w[st][l] * (+P_s|-P_t)[st][n] ------------------
    const int tx = t & 7, ty = t >> 3;   // tx: n/4, ty: l
    float rB[5];
    auto loadB = [&](int kbase) {
#pragma unroll
        for (int e = 0; e < 5; e++) {
            const int idx = t + e * 256;
            const int k = idx >> 5, j = idx & 31;
            const int kk = kbase + k;
            rB[e] = (kk < 100)
                ?  P[(size_t)(b * 100 + kk) * 512 + n0 + j]
                : -P[(size_t)(800 + b * 100 + (kk - 100)) * 512 + n0 + j];
        }
    };

    float acc[4] = {};
    loadB(0);
    for (int c5 = 0; c5 < 5; c5++) {
        __syncthreads();
#pragma unroll
        for (int e = 0; e < 5; e++) {
            const int idx = t + e * 256;
            Bs[idx] = rB[e];
        }
        __syncthreads();
        if (c5 < 4) loadB((c5 + 1) * 40);          // prefetch next chunk
#pragma unroll 8
        for (int k = 0; k < 40; k++) {
            const float ar = wbuf[(c5 * 40 + k) * 33 + ty];
            float br[4];
            *(float4*)br = *(const float4*)&Bs[k * 32 + tx * 4];
#pragma unroll
            for (int j = 0; j < 4; j++) acc[j] = fmaf(ar, br[j], acc[j]);
        }
    }

    const float s2 = 0.70710678118654752f;  // 1/sqrt(2)
    const int m = b * 128 + l0 + ty;
#pragma unroll
    for (int j = 0; j < 4; j++)
        unsafeAtomicAdd(&out[(size_t)m * 512 + n0 + tx * 4 + j], acc[j] * s2);
}

// ---------------- launch ----------------------------------------------------

extern "C" void kernel_launch(void* const* d_in, const int* in_sizes, int n_in,
                              void* d_out, int out_size, void* d_ws, size_t ws_size,
                              hipStream_t stream) {
    const float* query = (const float*)d_in[0];
    const float* src   = (const float*)d_in[1];
    const float* trg   = (const float*)d_in[2];
    const float* Wq    = (const float*)d_in[3];
    const float* bq    = (const float*)d_in[4];
    const float* Ws    = (const float*)d_in[5];
    const float* Wo    = (const float*)d_in[7];
    const float* bo    = (const float*)d_in[8];
    float* out = (float*)d_out;

    float* keys = (float*)d_ws;               // 1600*512 fp32 (UNBIASED)
    float* sc   = keys + 819200;              // 1024*256 fp32
    float* P    = sc   + 262144;              // 1600*512 fp32 = keys @ WoBot
    unsigned short* qh  = (unsigned short*)(P + 819200);  // 1024x512 bf16
    unsigned short* wqt = qh  + 524288;       // WqT 512x512
    unsigned short* wst = wqt + 262144;       // WsT 512x2048
    unsigned short* wot = wst + 1048576;      // WoT 512x1024

    k_prep<<<2592, 256, 0, stream>>>(Wq, Ws, Wo, wqt, wst, wot, keys);
    k_stageB<<<912, 256, 0, stream>>>(query, src, trg, wqt, wst, wot, bq, bo,
                                      qh, keys, out);
    k_stageC<<<328, 256, 0, stream>>>(qh, keys, wot + 512, sc, P);
    k_stageD<<<dim3(16, 8, 4), 256, 0, stream>>>(sc, P, out);
}

// Round 14
// 127.243 us; speedup vs baseline: 1.2056x; 1.0269x over previous
//
#include <hip/hip_runtime.h>
#include <math.h>

// DynamicAttention1 — round 23: R12 anchor + ONE change (cheap softmax).
// R22 re-anchor reproduced 130.7us -> R12's structure is genuinely ~5us
// better than all restructures (135-137). This round: byte-identical R12
// EXCEPT stageD softmax = R21's proven-correct cheap form (no max-subtract,
// |score|<~8 so fp32 exp is safe; single 5-step shfl_xor half-reduction,
// S in lanes 0-31 / T in 32-63). 24 shfl + 8 exp -> 5 shfl + 4 exp per
// row-iter. Single-variable A/B: isolates whether stageD softmax is on the
// critical path. Predict 130.7 -> ~124-128 if yes; null if hidden.

typedef __attribute__((ext_vector_type(8))) short s16x8;
typedef __attribute__((ext_vector_type(4))) float f32x4;

__device__ __forceinline__ unsigned short f2bf(float f) {
    unsigned int u = __float_as_uint(f);
    return (unsigned short)((u + 0x7fffu + ((u >> 16) & 1u)) >> 16);  // RNE
}

__device__ __forceinline__ s16x8 cvt8(const float* p) {
    float4 u = *(const float4*)p, w = *(const float4*)(p + 4);
    s16x8 o;
    o[0] = (short)f2bf(u.x); o[1] = (short)f2bf(u.y);
    o[2] = (short)f2bf(u.z); o[3] = (short)f2bf(u.w);
    o[4] = (short)f2bf(w.x); o[5] = (short)f2bf(w.y);
    o[6] = (short)f2bf(w.z); o[7] = (short)f2bf(w.w);
    return o;
}

// ---------------- prep: weight transposes + keys zero-init ------------------
__global__ __launch_bounds__(256) void k_prep(
    const float* __restrict__ Wq, const float* __restrict__ Ws,
    const float* __restrict__ Wo,
    unsigned short* __restrict__ WqT, unsigned short* __restrict__ WsT,
    unsigned short* __restrict__ WoT, float* __restrict__ keys) {
    __shared__ float tile[32][33];
    const int bid = blockIdx.x, t = threadIdx.x;

    if (bid < 1792) {                       // weight transpose-cast, 32x32 tiles
        const int id = bid;
        const float* W; unsigned short* O; int K, tk, tn;
        if (id < 256)       { W = Wq; O = WqT; K = 512;  tk = id >> 4;          tn = id & 15; }
        else if (id < 1280) { W = Ws; O = WsT; K = 2048; tk = (id - 256) >> 4;  tn = (id - 256) & 15; }
        else                { W = Wo; O = WoT; K = 1024; tk = (id - 1280) >> 4; tn = (id - 1280) & 15; }
        const int row = t >> 3, c4 = (t & 7) * 4;
        float4 v = *(const float4*)(W + (size_t)(tk * 32 + row) * 512 + tn * 32 + c4);
        tile[row][c4 + 0] = v.x; tile[row][c4 + 1] = v.y;
        tile[row][c4 + 2] = v.z; tile[row][c4 + 3] = v.w;
        __syncthreads();
        ushort4 o = make_ushort4(f2bf(tile[c4 + 0][row]), f2bf(tile[c4 + 1][row]),
                                 f2bf(tile[c4 + 2][row]), f2bf(tile[c4 + 3][row]));
        *(ushort4*)(O + (size_t)(tn * 32 + row) * K + tk * 32 + c4) = o;
    } else {                                // keys = 0 (split-K base, unbiased)
        const int f = ((bid - 1792) * 256 + t) * 4;
        *(float4*)(keys + f) = make_float4(0.f, 0.f, 0.f, 0.f);
    }
}

// ---------------- keys GEMM: A = [src;trg] fp32 (cvt in staging) ------------
// 64x64 tile, 4 waves 2x2; split-K x2, atomics onto zeroed keys.
__device__ __forceinline__ void gemm64_keys(
    const float* __restrict__ src, const float* __restrict__ trg,
    const unsigned short* __restrict__ BT, float* __restrict__ C,
    int m0, int n0, int kbase, unsigned short* As, unsigned short* Bs) {
    const int t = threadIdx.x;
    const int lane = t & 63, wid = t >> 6;
    const int wm = (wid & 1) * 32, wn = (wid >> 1) * 32;
    const int lr = lane & 15, lq = lane >> 4;
    const int r = t >> 3, c8 = (t & 7) * 8;

    const int ra_row = m0 + r, rb_row = m0 + r + 32;
    const float* arp = (ra_row < 800) ? (src + (size_t)ra_row * 2048)
                                      : (trg + (size_t)(ra_row - 800) * 2048);
    const float* brp = (rb_row < 800) ? (src + (size_t)rb_row * 2048)
                                      : (trg + (size_t)(rb_row - 800) * 2048);

    s16x8 ra0, ra1, rb0, rb1;
#define LDK(kt)                                                            \
    ra0 = cvt8(arp + (kt) + c8);                                           \
    ra1 = cvt8(brp + (kt) + c8);                                           \
    rb0 = *(const s16x8*)(BT + (size_t)(n0 + r)      * 2048 + (kt) + c8);  \
    rb1 = *(const s16x8*)(BT + (size_t)(n0 + r + 32) * 2048 + (kt) + c8);

    f32x4 acc[2][2] = {};
    LDK(kbase);
    for (int it = 0; it < 16; it++) {
        __syncthreads();
        *(s16x8*)&As[r * 72 + c8]        = ra0;
        *(s16x8*)&As[(r + 32) * 72 + c8] = ra1;
        *(s16x8*)&Bs[r * 72 + c8]        = rb0;
        *(s16x8*)&Bs[(r + 32) * 72 + c8] = rb1;
        __syncthreads();
        if (it < 15) { LDK(kbase + (it + 1) * 64); }  // prefetch
#pragma unroll
        for (int s = 0; s < 2; s++) {
            s16x8 a0 = *(const s16x8*)&As[(wm + lr) * 72      + s * 32 + lq * 8];
            s16x8 a1 = *(const s16x8*)&As[(wm + 16 + lr) * 72 + s * 32 + lq * 8];
            s16x8 b0 = *(const s16x8*)&Bs[(wn + lr) * 72      + s * 32 + lq * 8];
            s16x8 b1 = *(const s16x8*)&Bs[(wn + 16 + lr) * 72 + s * 32 + lq * 8];
            acc[0][0] = __builtin_amdgcn_mfma_f32_16x16x32_bf16(a0, b0, acc[0][0], 0, 0, 0);
            acc[0][1] = __builtin_amdgcn_mfma_f32_16x16x32_bf16(a0, b1, acc[0][1], 0, 0, 0);
            acc[1][0] = __builtin_amdgcn_mfma_f32_16x16x32_bf16(a1, b0, acc[1][0], 0, 0, 0);
            acc[1][1] = __builtin_amdgcn_mfma_f32_16x16x32_bf16(a1, b1, acc[1][1], 0, 0, 0);
        }
    }
#undef LDK
#pragma unroll
    for (int i = 0; i < 2; i++)
#pragma unroll
        for (int j = 0; j < 2; j++) {
            const int col = n0 + wn + j * 16 + lr;      // C/D: col=lane&15
            const int row = m0 + wm + i * 16 + lq * 4;  //      row=quad*4+reg
#pragma unroll
            for (int rr = 0; rr < 4; rr++)
                unsafeAtomicAdd(&C[(size_t)(row + rr) * 512 + col], acc[i][j][rr]);
        }
}

// ---------------- P GEMM: P = keys @ WoBot (direct fp32 store) --------------
// 64x64 tile, 4 waves 2x2, K=512 (8 iters). A = keys fp32 cvt, B = wot+512.
__device__ __forceinline__ void gemm64_P(
    const float* __restrict__ keys, const unsigned short* __restrict__ wotBot,
    float* __restrict__ P, int m0, int n0, unsigned short* As,
    unsigned short* Bs) {
    const int t = threadIdx.x;
    const int lane = t & 63, wid = t >> 6;
    const int wm = (wid & 1) * 32, wn = (wid >> 1) * 32;
    const int lr = lane & 15, lq = lane >> 4;
    const int r = t >> 3, c8 = (t & 7) * 8;

    s16x8 ra0, ra1, rb0, rb1;
#define LDP(kt)                                                               \
    ra0 = cvt8(keys + (size_t)(m0 + r)      * 512 + (kt) + c8);               \
    ra1 = cvt8(keys + (size_t)(m0 + r + 32) * 512 + (kt) + c8);               \
    rb0 = *(const s16x8*)(wotBot + (size_t)(n0 + r)      * 1024 + (kt) + c8); \
    rb1 = *(const s16x8*)(wotBot + (size_t)(n0 + r + 32) * 1024 + (kt) + c8);

    f32x4 acc[2][2] = {};
    LDP(0);
    for (int it = 0; it < 8; it++) {
        __syncthreads();
        *(s16x8*)&As[r * 72 + c8]        = ra0;
        *(s16x8*)&As[(r + 32) * 72 + c8] = ra1;
        *(s16x8*)&Bs[r * 72 + c8]        = rb0;
        *(s16x8*)&Bs[(r + 32) * 72 + c8] = rb1;
        __syncthreads();
        if (it < 7) { LDP((it + 1) * 64); }  // prefetch
#pragma unroll
        for (int s = 0; s < 2; s++) {
            s16x8 a0 = *(const s16x8*)&As[(wm + lr) * 72      + s * 32 + lq * 8];
            s16x8 a1 = *(const s16x8*)&As[(wm + 16 + lr) * 72 + s * 32 + lq * 8];
            s16x8 b0 = *(const s16x8*)&Bs[(wn + lr) * 72      + s * 32 + lq * 8];
            s16x8 b1 = *(const s16x8*)&Bs[(wn + 16 + lr) * 72 + s * 32 + lq * 8];
            acc[0][0] = __builtin_amdgcn_mfma_f32_16x16x32_bf16(a0, b0, acc[0][0], 0, 0, 0);
            acc[0][1] = __builtin_amdgcn_mfma_f32_16x16x32_bf16(a0, b1, acc[0][1], 0, 0, 0);
            acc[1][0] = __builtin_amdgcn_mfma_f32_16x16x32_bf16(a1, b0, acc[1][0], 0, 0, 0);
            acc[1][1] = __builtin_amdgcn_mfma_f32_16x16x32_bf16(a1, b1, acc[1][1], 0, 0, 0);
        }
    }
#undef LDP
#pragma unroll
    for (int i = 0; i < 2; i++)
#pragma unroll
        for (int j = 0; j < 2; j++) {
            const int col = n0 + wn + j * 16 + lr;
            const int row = m0 + wm + i * 16 + lq * 4;
#pragma unroll
            for (int rr = 0; rr < 4; rr++)
                P[(size_t)(row + rr) * 512 + col] = acc[i][j][rr];
        }
}

// 32x64 tile, 4 waves. A fp32 (cvt in staging). MODE 0: fp32+bias,
// 2: bf16+bias.
template <int MODE>
__device__ __forceinline__ void gemm32(
    const float* __restrict__ A, const unsigned short* __restrict__ BT,
    const float* __restrict__ bias, void* __restrict__ Cv,
    int m0, int n0, int KA, int KB, int N, int kiters,
    unsigned short* As, unsigned short* Bs) {
    const int t = threadIdx.x;
    const int lane = t & 63, wid = t >> 6;
    const int wm = (wid & 1) * 16, wn = (wid >> 1) * 32;
    const int lr = lane & 15, lq = lane >> 4;
    const int r = t >> 3, c8 = (t & 7) * 8;

    s16x8 ra, rb0, rb1;
#define LD32(kt)                                                            \
    ra  = cvt8(A + (size_t)(m0 + r) * KA + (kt) + c8);                      \
    rb0 = *(const s16x8*)(BT + (size_t)(n0 + r)      * KB + (kt) + c8);     \
    rb1 = *(const s16x8*)(BT + (size_t)(n0 + r + 32) * KB + (kt) + c8);

    f32x4 acc[2] = {};
    LD32(0);
    for (int it = 0; it < kiters; it++) {
        __syncthreads();
        *(s16x8*)&As[r * 72 + c8]        = ra;
        *(s16x8*)&Bs[r * 72 + c8]        = rb0;
        *(s16x8*)&Bs[(r + 32) * 72 + c8] = rb1;
        __syncthreads();
        if (it + 1 < kiters) { LD32((it + 1) * 64); }  // prefetch
#pragma unroll
        for (int s = 0; s < 2; s++) {
            s16x8 a0 = *(const s16x8*)&As[(wm + lr) * 72      + s * 32 + lq * 8];
            s16x8 b0 = *(const s16x8*)&Bs[(wn + lr) * 72      + s * 32 + lq * 8];
            s16x8 b1 = *(const s16x8*)&Bs[(wn + 16 + lr) * 72 + s * 32 + lq * 8];
            acc[0] = __builtin_amdgcn_mfma_f32_16x16x32_bf16(a0, b0, acc[0], 0, 0, 0);
            acc[1] = __builtin_amdgcn_mfma_f32_16x16x32_bf16(a0, b1, acc[1], 0, 0, 0);
        }
    }
#undef LD32
#pragma unroll
    for (int j = 0; j < 2; j++) {
        const int col = n0 + wn + j * 16 + lr;
        const int row = m0 + wm + lq * 4;
        const float bv = bias[col];
        if (MODE == 0) {
            float* C = (float*)Cv;
#pragma unroll
            for (int rr = 0; rr < 4; rr++)
                C[(size_t)(row + rr) * N + col] = acc[j][rr] + bv;
        } else {
            unsigned short* C = (unsigned short*)Cv;
#pragma unroll
            for (int rr = 0; rr < 4; rr++)
                C[(size_t)(row + rr) * N + col] = f2bf(acc[j][rr] + bv);
        }
    }
}

// ---------------- stage B: keys splitKx2 + qh + out_left --------------------
__global__ __launch_bounds__(256) void k_stageB(
    const float* __restrict__ query, const float* __restrict__ src,
    const float* __restrict__ trg, const unsigned short* __restrict__ WqT,
    const unsigned short* __restrict__ WsT, const unsigned short* __restrict__ WoT,
    const float* __restrict__ bq, const float* __restrict__ bo,
    unsigned short* __restrict__ qh, float* __restrict__ keys,
    float* __restrict__ out) {
    __shared__ __align__(16) unsigned short As[64 * 72];
    __shared__ __align__(16) unsigned short Bs[64 * 72];
    const int bid = blockIdx.x;
    if (bid < 400) {
        const int c = bid / 200, rem = bid % 200;
        const int mt = rem >> 3, nt = rem & 7;
        gemm64_keys(src, trg, WsT, keys, mt * 64, nt * 64, c * 1024, As, Bs);
    } else if (bid < 656) {
        const int r = bid - 400;
        const int mt = r >> 3, nt = r & 7;
        gemm32<2>(query, WqT, bq, qh, mt * 32, nt * 64, 512, 512, 512,
                  8, As, Bs);
    } else {
        const int r = bid - 656;
        const int mt = r >> 3, nt = r & 7;
        gemm32<0>(query, WoT, bo, out, mt * 32, nt * 64, 512, 1024, 512,
                  8, As, Bs);
    }
}

// ---------------- stage C: scgemm (128 blocks) + Pgemm (200 blocks) ---------
// scgemm: sc[b*128+l][n], cols 0..99 = qs/32, cols 128..227 = -qt/32.
// Pgemm:  P = keys @ WoBot, [1600][512] fp32 direct.
__global__ __launch_bounds__(256) void k_stageC(
    const unsigned short* __restrict__ qh, const float* __restrict__ keys,
    const unsigned short* __restrict__ wotBot, float* __restrict__ sc,
    float* __restrict__ P) {
    __shared__ __align__(16) unsigned short As[64 * 72];
    __shared__ __align__(16) unsigned short Bs[64 * 72];
    const int bid = blockIdx.x;
    const int t = threadIdx.x;

    if (bid >= 128) {                       // ---- Pgemm ----
        const int rem = bid - 128;
        gemm64_P(keys, wotBot, P, (rem >> 3) * 64, (rem & 7) * 64, As, Bs);
        return;
    }

    // ---- scgemm ----
    const int mt = bid >> 2, nt = bid & 3;
    const int m0 = mt * 32, b = mt >> 2, n0 = nt * 64;
    const int lane = t & 63, wid = t >> 6;
    const int wm = (wid & 1) * 16, wn = (wid >> 1) * 32;
    const int lr = lane & 15, lq = lane >> 4;
    const int r = t >> 3, c8 = (t & 7) * 8;

    const int nA = n0 + r, nB = n0 + r + 32;
    int kr0 = (nA < 128) ? (b * 100 + nA) : (800 + b * 100 + (nA - 128));
    int kr1 = (nB < 128) ? (b * 100 + nB) : (800 + b * 100 + (nB - 128));
    kr0 = kr0 > 1599 ? 1599 : kr0;
    kr1 = kr1 > 1599 ? 1599 : kr1;

    s16x8 ra, rb0, rb1;
#define LDSC(kt)                                                    \
    ra  = *(const s16x8*)(qh + (size_t)(m0 + r) * 512 + (kt) + c8); \
    rb0 = cvt8(keys + (size_t)kr0 * 512 + (kt) + c8);               \
    rb1 = cvt8(keys + (size_t)kr1 * 512 + (kt) + c8);

    f32x4 acc[2] = {};
    LDSC(0);
    for (int it = 0; it < 8; it++) {
        __syncthreads();
        *(s16x8*)&As[r * 72 + c8]        = ra;
        *(s16x8*)&Bs[r * 72 + c8]        = rb0;
        *(s16x8*)&Bs[(r + 32) * 72 + c8] = rb1;
        __syncthreads();
        if (it < 7) { LDSC((it + 1) * 64); }
#pragma unroll
        for (int s = 0; s < 2; s++) {
            s16x8 a0 = *(const s16x8*)&As[(wm + lr) * 72      + s * 32 + lq * 8];
            s16x8 b0 = *(const s16x8*)&Bs[(wn + lr) * 72      + s * 32 + lq * 8];
            s16x8 b1 = *(const s16x8*)&Bs[(wn + 16 + lr) * 72 + s * 32 + lq * 8];
            acc[0] = __builtin_amdgcn_mfma_f32_16x16x32_bf16(a0, b0, acc[0], 0, 0, 0);
            acc[1] = __builtin_amdgcn_mfma_f32_16x16x32_bf16(a0, b1, acc[1], 0, 0, 0);
        }
    }
#undef LDSC
#pragma unroll
    for (int j = 0; j < 2; j++) {
        const int col = n0 + wn + j * 16 + lr;
        const int row = m0 + wm + lq * 4;
        const float scale = (col >= 128) ? -(1.0f / 32.0f) : (1.0f / 32.0f);
#pragma unroll
        for (int rr = 0; rr < 4; rr++)
            sc[(size_t)(row + rr) * 256 + col] = acc[j][rr] * scale;
    }
}

// ---------------- stage D: cheap softmax + wP GEMM -> atomic into out -------
// grid (16 n-tiles, 8 b, 4 l-tiles) = 512 blocks of 32(l) x 32(n), K=200.
// Softmax WITHOUT max-subtraction (|score|<~8 -> fp32 exp safe); S-cols in
// lanes 0..31, T-cols in 32..63 -> one 5-step shfl_xor reduces each half.
__global__ __launch_bounds__(256) void k_stageD(
    const float* __restrict__ sc, const float* __restrict__ P,
    float* __restrict__ out) {
    __shared__ float wbuf[200 * 33];     // [st][l], pad 33
    __shared__ float Bs[40 * 32];        // [k][n]

    const int t = threadIdx.x;
    const int b = blockIdx.y;
    const int n0 = blockIdx.x * 32;
    const int l0 = blockIdx.z * 32;
    const int wave = t >> 6, lane = t & 63;

    // ---- softmax (no-max, half-reduce) ----
    for (int i = 0; i < 8; i++) {
        const int li = wave * 8 + i;                  // 0..31
        const float4 v = *(const float4*)(
            sc + (size_t)(b * 128 + l0 + li) * 256 + lane * 4);
        const float vv[4] = {v.x, v.y, v.z, v.w};
        const int c0 = lane * 4;
        float e[4], s = 0.f;
#pragma unroll
        for (int j = 0; j < 4; j++) {
            const int col = c0 + j;
            const bool valid = (col < 100) | (col >= 128 && col < 228);
            e[j] = valid ? __expf(vv[j]) : 0.f;
            s += e[j];
        }
#pragma unroll
        for (int off = 16; off > 0; off >>= 1) s += __shfl_xor(s, off);
        const float inv = 1.f / s;                    // lanes<32: 1/sS; >=32: 1/sT
#pragma unroll
        for (int j = 0; j < 4; j++) {
            const int col = c0 + j;
            if (col < 100) wbuf[col * 33 + li] = e[j] * inv;
            else if (col >= 128 && col < 228)
                wbuf[(100 + col - 128) * 33 + li] = e[j] * inv;
        }
    }
    __syncthreads();

    // ---- GEMM: acc[l][n] += w[st][l] * (+P_s|-P_t)[st][n] ------------------
    const int tx = t & 7, ty = t >> 3;   // tx: n/4, ty: l
    float rB[5];
    auto loadB = [&](int kbase) {
#pragma unroll
        for (int e2 = 0; e2 < 5; e2++) {
            const int idx = t + e2 * 256;
            const int k = idx >> 5, j = idx & 31;
            const int kk = kbase + k;
            rB[e2] = (kk < 100)
                ?  P[(size_t)(b * 100 + kk) * 512 + n0 + j]
                : -P[(size_t)(800 + b * 100 + (kk - 100)) * 512 + n0 + j];
        }
    };

    float acc[4] = {};
    loadB(0);
    for (int c5 = 0; c5 < 5; c5++) {
        __syncthreads();
#pragma unroll
        for (int e2 = 0; e2 < 5; e2++) {
            const int idx = t + e2 * 256;
            Bs[idx] = rB[e2];
        }
        __syncthreads();
        if (c5 < 4) loadB((c5 + 1) * 40);          // prefetch next chunk
#pragma unroll 8
        for (int k = 0; k < 40; k++) {
            const float ar = wbuf[(c5 * 40 + k) * 33 + ty];
            float br[4];
            *(float4*)br = *(const float4*)&Bs[k * 32 + tx * 4];
#pragma unroll
            for (int j = 0; j < 4; j++) acc[j] = fmaf(ar, br[j], acc[j]);
        }
    }

    const float s2 = 0.70710678118654752f;  // 1/sqrt(2)
    const int m = b * 128 + l0 + ty;
#pragma unroll
    for (int j = 0; j < 4; j++)
        unsafeAtomicAdd(&out[(size_t)m * 512 + n0 + tx * 4 + j], acc[j] * s2);
}

// ---------------- launch ----------------------------------------------------

extern "C" void kernel_launch(void* const* d_in, const int* in_sizes, int n_in,
                              void* d_out, int out_size, void* d_ws, size_t ws_size,
                              hipStream_t stream) {
    const float* query = (const float*)d_in[0];
    const float* src   = (const float*)d_in[1];
    const float* trg   = (const float*)d_in[2];
    const float* Wq    = (const float*)d_in[3];
    const float* bq    = (const float*)d_in[4];
    const float* Ws    = (const float*)d_in[5];
    const float* Wo    = (const float*)d_in[7];
    const float* bo    = (const float*)d_in[8];
    float* out = (float*)d_out;

    float* keys = (float*)d_ws;               // 1600*512 fp32 (UNBIASED)
    float* sc   = keys + 819200;              // 1024*256 fp32
    float* P    = sc   + 262144;              // 1600*512 fp32 = keys @ WoBot
    unsigned short* qh  = (unsigned short*)(P + 819200);  // 1024x512 bf16
    unsigned short* wqt = qh  + 524288;       // WqT 512x512
    unsigned short* wst = wqt + 262144;       // WsT 512x2048
    unsigned short* wot = wst + 1048576;      // WoT 512x1024

    k_prep<<<2592, 256, 0, stream>>>(Wq, Ws, Wo, wqt, wst, wot, keys);
    k_stageB<<<912, 256, 0, stream>>>(query, src, trg, wqt, wst, wot, bq, bo,
                                      qh, keys, out);
    k_stageC<<<328, 256, 0, stream>>>(qh, keys, wot + 512, sc, P);
    k_stageD<<<dim3(16, 8, 4), 256, 0, stream>>>(sc, P, out);
}